// Round 1
// baseline (3386.231 us; speedup 1.0000x reference)
//
#include <hip/hip_runtime.h>
#include <hip/hip_bf16.h>

// ---------------------------------------------------------------------------
// PCELayer: 8 expert conv3x3+GN+SiLU+residual, Fourier-feature router,
// patch-wise combine, then 1x1 -> dw3x3 -> 1x1(stride2) bottleneck w/ GN+SiLU.
//
// R1 plan: correct fp32 pipeline. Expert convs (155 GFLOP) on fp32 VALU; one
// block owns an (e,b,group) GN slice register-resident (512 thr x 128 accs),
// folds residual via sum_e(softmax)=1, atomicAdds into `combined`.
// Workspace layout (needs ~168 MB):
//   [0,512)       wts (gate softmax)        [1024,4096) stats1/2/3 (zeroed)
//   [16K, +33.5M) combined fp32  (reused as h3_raw)
//   slotA 67MB    h1_raw bf16 -> h2_raw bf16
//   slotB 67MB    h1n bf16    -> h2n bf16
// ---------------------------------------------------------------------------

#define B_ 16
#define CIN_ 128
#define COUT_ 128
#define H_ 64
#define W_ 64
#define HW_ 4096
#define E_ 8
#define FF_ 8
#define GC_ 32
#define HID_ 64
#define HC_ 512

typedef __hip_bfloat16 bf16;

__device__ __forceinline__ float siluf(float v) { return v / (1.f + __expf(-v)); }
__device__ __forceinline__ float bf2f(bf16 v) { return __bfloat162float(v); }
__device__ __forceinline__ bf16 f2bf(float v) { return __float2bfloat16(v); }

// ---------------- router gate: 16 patches, tiny MLP + softmax --------------
__global__ void gate_kernel(const float* __restrict__ w1, const float* __restrict__ b1,
                            const float* __restrict__ w2, const float* __restrict__ b2,
                            float* __restrict__ wts) {
  int p = threadIdx.x;
  if (p >= 16) return;
  int i = p >> 2, j = p & 3;
  float cy = (i + 0.5f) * 0.25f;
  float cx = (j + 0.5f) * 0.25f;
  float feats[GC_];
#pragma unroll
  for (int f = 0; f < FF_; ++f) {
    float fr = 3.14159265358979f * (float)(1 << f);  // 2^f * pi (exact scaling)
    float ay = cy * fr, ax = cx * fr;
    feats[f] = sinf(ay);
    feats[FF_ + f] = cosf(ay);
    feats[2 * FF_ + f] = sinf(ax);
    feats[3 * FF_ + f] = cosf(ax);
  }
  float hid[HID_];
  for (int k = 0; k < HID_; ++k) {
    float a = b1[k];
#pragma unroll
    for (int m = 0; m < GC_; ++m) a = fmaf(feats[m], w1[m * HID_ + k], a);
    hid[k] = siluf(a);
  }
  float lg[E_];
  float mx = -1e30f;
#pragma unroll
  for (int e = 0; e < E_; ++e) {
    float a = b2[e];
    for (int k = 0; k < HID_; ++k) a = fmaf(hid[k], w2[k * E_ + e], a);
    lg[e] = a;
    mx = fmaxf(mx, a);
  }
  float s = 0.f;
#pragma unroll
  for (int e = 0; e < E_; ++e) { lg[e] = __expf(lg[e] - mx); s += lg[e]; }
  float inv = 1.f / s;
#pragma unroll
  for (int e = 0; e < E_; ++e) wts[p * E_ + e] = lg[e] * inv;
}

// ---------------- combined = x (residual base, since sum_e wts = 1) --------
__global__ void copy_kernel(const float4* __restrict__ src, float4* __restrict__ dst, int n4) {
  for (int i = blockIdx.x * blockDim.x + threadIdx.x; i < n4; i += gridDim.x * blockDim.x)
    dst[i] = src[i];
}

// ---------------- expert conv3x3 + GN + SiLU + weighted combine ------------
// grid: E*B*8 blocks (e,b,group-of-16-ch), 512 threads.
// Each thread: 2 chunks of (h, w4) -> acc[2][16][4] = 128 fp32 registers.
__global__ __launch_bounds__(512, 2) void expert_kernel(
    const float* __restrict__ x, const float* __restrict__ w_exp,
    const float* __restrict__ gns, const float* __restrict__ gnb,
    const float* __restrict__ wts, float* __restrict__ combined) {
  __shared__ float wlds[2048 * 12];  // 16ch x 128cin, 9 taps padded to 12 (98304 B)
  __shared__ float red[16];
  int blk = blockIdx.x;
  int g = blk & 7, b = (blk >> 3) & 15, e = blk >> 7;
  int t = threadIdx.x;

  const float* wsrc = w_exp + ((size_t)(e * COUT_ + g * 16) * CIN_) * 9;
  for (int pair = t; pair < 2048; pair += 512) {
    const float* sp = wsrc + pair * 9;
    float* dp = wlds + pair * 12;
#pragma unroll
    for (int q = 0; q < 9; ++q) dp[q] = sp[q];
  }
  __syncthreads();

  float acc[128];
#pragma unroll
  for (int i = 0; i < 128; ++i) acc[i] = 0.f;

  const float* xb = x + (size_t)b * CIN_ * HW_;

#pragma unroll
  for (int ch = 0; ch < 2; ++ch) {
    int idx = t + ch * 512;           // 0..1023
    int h = idx >> 4;                 // 0..63
    int w4 = (idx & 15) << 2;         // 0..60
    for (int cin = 0; cin < CIN_; ++cin) {
      const float* xp = xb + cin * HW_;
      float xr[3][6];
#pragma unroll
      for (int r = 0; r < 3; ++r) {
        int hh = h + r - 1;
        bool hv = (unsigned)hh < 64u;
        const float* row = xp + hh * W_;
        float4 mid = hv ? *(const float4*)(row + w4) : make_float4(0.f, 0.f, 0.f, 0.f);
        xr[r][1] = mid.x; xr[r][2] = mid.y; xr[r][3] = mid.z; xr[r][4] = mid.w;
        xr[r][0] = (hv && w4 > 0) ? row[w4 - 1] : 0.f;
        xr[r][5] = (hv && w4 + 4 < W_) ? row[w4 + 4] : 0.f;
      }
#pragma unroll
      for (int c = 0; c < 16; ++c) {
        const float* wp = wlds + (c * CIN_ + cin) * 12;
        float* a = acc + (ch * 16 + c) * 4;
#pragma unroll
        for (int r = 0; r < 3; ++r) {
#pragma unroll
          for (int s2 = 0; s2 < 3; ++s2) {
            float wv = wp[r * 3 + s2];
#pragma unroll
            for (int q = 0; q < 4; ++q)
              a[q] = fmaf(xr[r][s2 + q], wv, a[q]);
          }
        }
      }
    }
  }

  // GN stats over all 16ch x 4096 values held by this block
  float s = 0.f, ss = 0.f;
#pragma unroll
  for (int i = 0; i < 128; ++i) { s += acc[i]; ss += acc[i] * acc[i]; }
#pragma unroll
  for (int off = 32; off > 0; off >>= 1) {
    s += __shfl_down(s, off, 64);
    ss += __shfl_down(ss, off, 64);
  }
  int wave = t >> 6;
  if ((t & 63) == 0) { red[wave * 2] = s; red[wave * 2 + 1] = ss; }
  __syncthreads();
  float S = 0.f, SS = 0.f;
#pragma unroll
  for (int w8 = 0; w8 < 8; ++w8) { S += red[w8 * 2]; SS += red[w8 * 2 + 1]; }
  float mean = S * (1.f / 65536.f);
  float var = SS * (1.f / 65536.f) - mean * mean;
  float rstd = rsqrtf(var + 1e-5f);

  float* cb = combined + (size_t)(b * COUT_ + g * 16) * HW_;
#pragma unroll
  for (int ch = 0; ch < 2; ++ch) {
    int idx = t + ch * 512;
    int h = idx >> 4, w4 = (idx & 15) << 2;
    int pid = (h >> 4) * 4 + (w4 >> 4);
    float wt = wts[pid * E_ + e];
#pragma unroll
    for (int c = 0; c < 16; ++c) {
      float scale = gns[e * COUT_ + g * 16 + c] * rstd;
      float beta = gnb[e * COUT_ + g * 16 + c];
      const float* a = acc + (ch * 16 + c) * 4;
#pragma unroll
      for (int q = 0; q < 4; ++q) {
        float v = (a[q] - mean) * scale + beta;
        atomicAdd(cb + c * HW_ + h * W_ + w4 + q, siluf(v) * wt);
      }
    }
  }
}

// ---------------- pw1: 1x1 conv 128->512 + partial GN stats ----------------
// grid: B*64 (b, tile of 8 out-ch), 256 threads, 16 positions each.
__global__ __launch_bounds__(256, 2) void pw1_kernel(
    const float* __restrict__ combined, const float* __restrict__ w_pw1,
    bf16* __restrict__ h1_raw, float* __restrict__ stats1) {
  __shared__ float red[8];
  int blk = blockIdx.x;
  int ot = blk & 63, b = blk >> 6;
  int o0 = ot * 8;
  int t = threadIdx.x;
  float acc[8][16];
#pragma unroll
  for (int k = 0; k < 8; ++k)
#pragma unroll
    for (int j = 0; j < 16; ++j) acc[k][j] = 0.f;
  const float* cbase = combined + (size_t)b * COUT_ * HW_;
  for (int c = 0; c < COUT_; ++c) {
    float wv[8];
#pragma unroll
    for (int k = 0; k < 8; ++k) wv[k] = w_pw1[(o0 + k) * COUT_ + c];
    const float* cp = cbase + c * HW_;
#pragma unroll
    for (int j = 0; j < 16; ++j) {
      float in = cp[t + j * 256];
#pragma unroll
      for (int k = 0; k < 8; ++k) acc[k][j] = fmaf(in, wv[k], acc[k][j]);
    }
  }
  float s = 0.f, ss = 0.f;
#pragma unroll
  for (int k = 0; k < 8; ++k)
#pragma unroll
    for (int j = 0; j < 16; ++j) {
      float v = acc[k][j];
      s += v; ss += v * v;
      h1_raw[(size_t)(b * HC_ + o0 + k) * HW_ + t + j * 256] = f2bf(v);
    }
#pragma unroll
  for (int off = 32; off > 0; off >>= 1) {
    s += __shfl_down(s, off, 64);
    ss += __shfl_down(ss, off, 64);
  }
  int wave = t >> 6;
  if ((t & 63) == 0) { red[wave * 2] = s; red[wave * 2 + 1] = ss; }
  __syncthreads();
  if (t == 0) {
    float S = red[0] + red[2] + red[4] + red[6];
    float SS = red[1] + red[3] + red[5] + red[7];
    int bg = b * 8 + (ot >> 3);
    atomicAdd(&stats1[bg * 2], S);
    atomicAdd(&stats1[bg * 2 + 1], SS);
  }
}

// ---------------- normalize+SiLU for h1/h2 (C=512, 64 ch per group) --------
__global__ void norm_kernel(const bf16* __restrict__ raw, const float* __restrict__ stats,
                            const float* __restrict__ gs, const float* __restrict__ gb,
                            bf16* __restrict__ outb) {
  const int total = B_ * HC_ * HW_;
  for (int idx = blockIdx.x * blockDim.x + threadIdx.x; idx < total; idx += gridDim.x * blockDim.x) {
    int c = (idx >> 12) & 511;
    int b = idx >> 21;
    int bg = b * 8 + (c >> 6);
    float S = stats[bg * 2], SS = stats[bg * 2 + 1];
    float mean = S * (1.f / 262144.f);
    float var = SS * (1.f / 262144.f) - mean * mean;
    float rstd = rsqrtf(var + 1e-5f);
    float v = bf2f(raw[idx]);
    v = (v - mean) * rstd * gs[c] + gb[c];
    outb[idx] = f2bf(siluf(v));
  }
}

// ---------------- depthwise 3x3 + partial GN stats -------------------------
__global__ __launch_bounds__(256) void dw_kernel(
    const bf16* __restrict__ h1n, const float* __restrict__ w_dw,
    bf16* __restrict__ h2_raw, float* __restrict__ stats2) {
  __shared__ float red[8];
  int blk = blockIdx.x;  // b*512 + hc
  int hc = blk & 511, b = blk >> 9;
  int t = threadIdx.x;
  const bf16* in = h1n + (size_t)blk * HW_;
  bf16* outp = h2_raw + (size_t)blk * HW_;
  float wv[9];
#pragma unroll
  for (int i = 0; i < 9; ++i) wv[i] = w_dw[hc * 9 + i];
  float s = 0.f, ss = 0.f;
  for (int j = 0; j < 16; ++j) {
    int pos = t + j * 256;
    int h = pos >> 6, w = pos & 63;
    float acc = 0.f;
#pragma unroll
    for (int r = 0; r < 3; ++r) {
      int hh = h + r - 1;
      if ((unsigned)hh < 64u) {
#pragma unroll
        for (int s2 = 0; s2 < 3; ++s2) {
          int ww = w + s2 - 1;
          if ((unsigned)ww < 64u)
            acc = fmaf(bf2f(in[hh * 64 + ww]), wv[r * 3 + s2], acc);
        }
      }
    }
    outp[pos] = f2bf(acc);
    s += acc; ss += acc * acc;
  }
#pragma unroll
  for (int off = 32; off > 0; off >>= 1) {
    s += __shfl_down(s, off, 64);
    ss += __shfl_down(ss, off, 64);
  }
  int wave = t >> 6;
  if ((t & 63) == 0) { red[wave * 2] = s; red[wave * 2 + 1] = ss; }
  __syncthreads();
  if (t == 0) {
    float S = red[0] + red[2] + red[4] + red[6];
    float SS = red[1] + red[3] + red[5] + red[7];
    int bg = b * 8 + (hc >> 6);
    atomicAdd(&stats2[bg * 2], S);
    atomicAdd(&stats2[bg * 2 + 1], SS);
  }
}

// ---------------- pw2: 1x1 stride-2 conv 512->128 + partial GN stats -------
// grid: B*32 (b, tile of 4 out-ch), 256 threads, 4 positions each (32x32 out)
__global__ __launch_bounds__(256) void pw2_kernel(
    const bf16* __restrict__ h2n, const float* __restrict__ w_pw2,
    float* __restrict__ h3_raw, float* __restrict__ stats3) {
  __shared__ float red[8];
  int blk = blockIdx.x;  // b*32 + ot
  int ot = blk & 31, b = blk >> 5;
  int o0 = ot * 4;
  int t = threadIdx.x;
  float acc[4][4];
#pragma unroll
  for (int k = 0; k < 4; ++k)
#pragma unroll
    for (int j = 0; j < 4; ++j) acc[k][j] = 0.f;
  const bf16* ib = h2n + (size_t)b * HC_ * HW_;
  for (int c = 0; c < HC_; ++c) {
    float wv[4];
#pragma unroll
    for (int k = 0; k < 4; ++k) wv[k] = w_pw2[(o0 + k) * HC_ + c];
    const bf16* cp = ib + c * HW_;
#pragma unroll
    for (int j = 0; j < 4; ++j) {
      int pos = t + j * 256;          // 0..1023
      int h2 = pos >> 5, w2 = pos & 31;
      float in = bf2f(cp[h2 * 128 + w2 * 2]);
#pragma unroll
      for (int k = 0; k < 4; ++k) acc[k][j] = fmaf(in, wv[k], acc[k][j]);
    }
  }
  float s = 0.f, ss = 0.f;
#pragma unroll
  for (int k = 0; k < 4; ++k)
#pragma unroll
    for (int j = 0; j < 4; ++j) {
      int pos = t + j * 256;
      float v = acc[k][j];
      s += v; ss += v * v;
      h3_raw[(size_t)(b * COUT_ + o0 + k) * 1024 + pos] = v;
    }
#pragma unroll
  for (int off = 32; off > 0; off >>= 1) {
    s += __shfl_down(s, off, 64);
    ss += __shfl_down(ss, off, 64);
  }
  int wave = t >> 6;
  if ((t & 63) == 0) { red[wave * 2] = s; red[wave * 2 + 1] = ss; }
  __syncthreads();
  if (t == 0) {
    float S = red[0] + red[2] + red[4] + red[6];
    float SS = red[1] + red[3] + red[5] + red[7];
    int bg = b * 8 + (o0 >> 4);
    atomicAdd(&stats3[bg * 2], S);
    atomicAdd(&stats3[bg * 2 + 1], SS);
  }
}

// ---------------- final GN+SiLU -> d_out (fp32) ----------------------------
__global__ void out_kernel(const float* __restrict__ h3, const float* __restrict__ stats,
                           const float* __restrict__ gs, const float* __restrict__ gb,
                           float* __restrict__ out) {
  const int total = B_ * COUT_ * 1024;
  for (int idx = blockIdx.x * blockDim.x + threadIdx.x; idx < total; idx += gridDim.x * blockDim.x) {
    int c = (idx >> 10) & 127;
    int b = idx >> 17;
    int bg = b * 8 + (c >> 4);
    float S = stats[bg * 2], SS = stats[bg * 2 + 1];
    float mean = S * (1.f / 16384.f);
    float var = SS * (1.f / 16384.f) - mean * mean;
    float rstd = rsqrtf(var + 1e-5f);
    float v = (h3[idx] - mean) * rstd * gs[c] + gb[c];
    out[idx] = siluf(v);
  }
}

extern "C" void kernel_launch(void* const* d_in, const int* in_sizes, int n_in,
                              void* d_out, int out_size, void* d_ws, size_t ws_size,
                              hipStream_t stream) {
  const float* x = (const float*)d_in[0];
  const float* w_exp = (const float*)d_in[1];
  const float* gn_exp_s = (const float*)d_in[2];
  const float* gn_exp_b = (const float*)d_in[3];
  const float* w1 = (const float*)d_in[4];
  const float* b1 = (const float*)d_in[5];
  const float* w2 = (const float*)d_in[6];
  const float* b2 = (const float*)d_in[7];
  const float* w_pw1 = (const float*)d_in[8];
  const float* gn1_s = (const float*)d_in[9];
  const float* gn1_b = (const float*)d_in[10];
  const float* w_dw = (const float*)d_in[11];
  const float* gn2_s = (const float*)d_in[12];
  const float* gn2_b = (const float*)d_in[13];
  const float* w_pw2 = (const float*)d_in[14];
  const float* gn3_s = (const float*)d_in[15];
  const float* gn3_b = (const float*)d_in[16];

  char* ws = (char*)d_ws;
  const size_t COMBINED_OFF = 16384;
  const size_t COMBINED_BYTES = (size_t)B_ * COUT_ * HW_ * 4;     // 33.5 MB
  const size_t SLOT_BYTES = (size_t)B_ * HC_ * HW_ * 2;           // 67.1 MB
  const size_t NEEDED = COMBINED_OFF + COMBINED_BYTES + 2 * SLOT_BYTES;
  if (ws_size < NEEDED) return;  // fail loudly (output stays poisoned)

  float* wts = (float*)ws;
  float* stats1 = (float*)(ws + 1024);
  float* stats2 = (float*)(ws + 2048);
  float* stats3 = (float*)(ws + 3072);
  float* combined = (float*)(ws + COMBINED_OFF);
  char* slotA = ws + COMBINED_OFF + COMBINED_BYTES;
  char* slotB = slotA + SLOT_BYTES;
  bf16* h1_raw = (bf16*)slotA;
  bf16* h1n = (bf16*)slotB;
  bf16* h2_raw = (bf16*)slotA;   // h1_raw dead after norm1
  bf16* h2n = (bf16*)slotB;      // h1n dead after dw
  float* h3_raw = combined;      // combined dead after pw1

  hipMemsetAsync(ws, 0, 4096, stream);  // zero stats (ws is poisoned 0xAA)
  gate_kernel<<<1, 64, 0, stream>>>(w1, b1, w2, b2, wts);
  copy_kernel<<<2048, 256, 0, stream>>>((const float4*)x, (float4*)combined,
                                        B_ * CIN_ * HW_ / 4);
  expert_kernel<<<E_ * B_ * 8, 512, 0, stream>>>(x, w_exp, gn_exp_s, gn_exp_b, wts, combined);
  pw1_kernel<<<B_ * 64, 256, 0, stream>>>(combined, w_pw1, h1_raw, stats1);
  norm_kernel<<<2048, 256, 0, stream>>>(h1_raw, stats1, gn1_s, gn1_b, h1n);
  dw_kernel<<<B_ * HC_, 256, 0, stream>>>(h1n, w_dw, h2_raw, stats2);
  norm_kernel<<<2048, 256, 0, stream>>>(h2_raw, stats2, gn2_s, gn2_b, h2n);
  pw2_kernel<<<B_ * 32, 256, 0, stream>>>(h2n, w_pw2, h3_raw, stats3);
  out_kernel<<<1024, 256, 0, stream>>>(h3_raw, stats3, gn3_s, gn3_b, (float*)d_out);
}

// Round 2
// 915.525 us; speedup vs baseline: 3.6987x; 3.6987x over previous
//
#include <hip/hip_runtime.h>
#include <hip/hip_bf16.h>

// ---------------------------------------------------------------------------
// PCELayer. R2: expert conv3x3 -> implicit-GEMM MFMA (bf16 in, fp32 acc).
//   xT[b][h][cg(16)][w(64)][lo(8)] bf16 (channels-last, 8-ci interleave)
//   wT[e][tap(9)][cg(16)][co(128)][lo(8)] bf16
//   conv_mfma: block=(e,b,2-row tile), 128co x 128pos, K=1152
//              = 2 ci-halves x 9 taps x 2 k-steps of 32. GN partial stats
//              via atomicAdd; raw conv out ys bf16 [e][b][co][4096].
//   combine: out = x + sum_e silu(gn(ys_e)) * wt_e   (sum_e wt = 1)
// Workspace (= R1's 167.8 MB):
//   [0,512) wts | +1024 stats1 | +2048 stats2 | +3072 stats3 | +4096 statsE(8K)
//   +16384: combined fp32 33.5MB  (aliases xT 16.8MB + wT 2.4MB; also h3_raw)
//   slotA+slotB 134.2MB: ys  -> later h1_raw/h2_raw (A), h1n/h2n (B)
// ---------------------------------------------------------------------------

#define B_ 16
#define CIN_ 128
#define COUT_ 128
#define H_ 64
#define W_ 64
#define HW_ 4096
#define E_ 8
#define FF_ 8
#define GC_ 32
#define HID_ 64
#define HC_ 512

typedef __hip_bfloat16 bf16;
typedef __bf16 bf16x8 __attribute__((ext_vector_type(8)));
typedef float f32x4 __attribute__((ext_vector_type(4)));

__device__ __forceinline__ float siluf(float v) { return v / (1.f + __expf(-v)); }
__device__ __forceinline__ float bf2f(bf16 v) { return __bfloat162float(v); }
__device__ __forceinline__ bf16 f2bf(float v) { return __float2bfloat16(v); }

// ---------------- router gate ----------------------------------------------
__global__ void gate_kernel(const float* __restrict__ w1, const float* __restrict__ b1,
                            const float* __restrict__ w2, const float* __restrict__ b2,
                            float* __restrict__ wts) {
  int p = threadIdx.x;
  if (p >= 16) return;
  int i = p >> 2, j = p & 3;
  float cy = (i + 0.5f) * 0.25f;
  float cx = (j + 0.5f) * 0.25f;
  float feats[GC_];
#pragma unroll
  for (int f = 0; f < FF_; ++f) {
    float fr = 3.14159265358979f * (float)(1 << f);
    float ay = cy * fr, ax = cx * fr;
    feats[f] = sinf(ay);
    feats[FF_ + f] = cosf(ay);
    feats[2 * FF_ + f] = sinf(ax);
    feats[3 * FF_ + f] = cosf(ax);
  }
  float hid[HID_];
  for (int k = 0; k < HID_; ++k) {
    float a = b1[k];
#pragma unroll
    for (int m = 0; m < GC_; ++m) a = fmaf(feats[m], w1[m * HID_ + k], a);
    hid[k] = siluf(a);
  }
  float lg[E_];
  float mx = -1e30f;
#pragma unroll
  for (int e = 0; e < E_; ++e) {
    float a = b2[e];
    for (int k = 0; k < HID_; ++k) a = fmaf(hid[k], w2[k * E_ + e], a);
    lg[e] = a;
    mx = fmaxf(mx, a);
  }
  float s = 0.f;
#pragma unroll
  for (int e = 0; e < E_; ++e) { lg[e] = __expf(lg[e] - mx); s += lg[e]; }
  float inv = 1.f / s;
#pragma unroll
  for (int e = 0; e < E_; ++e) wts[p * E_ + e] = lg[e] * inv;
}

// ---------------- x -> channels-last bf16 ----------------------------------
// xT[b][h][cg(16)][w(64)][lo(8)], one block per (b,h)
__global__ __launch_bounds__(256) void xt_kernel(const float* __restrict__ x,
                                                 bf16* __restrict__ xT) {
  __shared__ float t[128][65];
  int b = blockIdx.x >> 6, h = blockIdx.x & 63;
  int tid = threadIdx.x;
  int w = tid & 63, c4 = tid >> 6;
  const float* xb = x + ((size_t)(b * 128) * 64 + h) * 64;
#pragma unroll 4
  for (int rep = 0; rep < 32; ++rep) {
    int ci = rep * 4 + c4;
    t[ci][w] = xb[(size_t)ci * HW_ + w];
  }
  __syncthreads();
  bf16* dst = xT + (size_t)(b * 64 + h) * 8192;
#pragma unroll 4
  for (int rep = 0; rep < 32; ++rep) {
    int o = rep * 256 + tid;
    int cg = o >> 9, w2 = (o >> 3) & 63, lo = o & 7;
    dst[o] = f2bf(t[cg * 8 + lo][w2]);
  }
}

// ---------------- w_exp -> wT bf16 -----------------------------------------
// wT[e][tap][cg(16)][co(128)][lo(8)], total 1,179,648 elements
__global__ void wt_kernel(const float* __restrict__ w_exp, bf16* __restrict__ wT) {
  int idx = blockIdx.x * 256 + threadIdx.x;
  if (idx >= 1179648) return;
  int lo = idx & 7;
  int co = (idx >> 3) & 127;
  int cg = (idx >> 10) & 15;
  int rest = idx >> 14;
  int tap = rest % 9, e = rest / 9;
  int ci = cg * 8 + lo;
  wT[idx] = f2bf(w_exp[(((size_t)(e * 128 + co) * 128 + ci) * 9) + tap]);
}

// ---------------- expert conv via MFMA -------------------------------------
// grid: e(8) x b(16) x pt(32).  256 thr = 4 waves. Output 128co x 128pos
// (rows h0,h0+1 x 64 w). Wave: h_local=wave>>1, wbase=(wave&1)*32,
// 8 m-tiles x 2 n-tiles, K looped as half(2) x tap(9) x kc(2).
// LDS skewed +16B per cg chunk to keep ds_read_b128 at free 2-way aliasing.
__global__ __launch_bounds__(256, 2) void conv_mfma(
    const bf16* __restrict__ xT, const bf16* __restrict__ wT,
    float* __restrict__ statsE, bf16* __restrict__ ys) {
  __shared__ __align__(16) char xls[8 * 4112];   // [cg: +4112B] [r(4)][w(64)] x16B
  __shared__ __align__(16) char wls[8 * 2064];   // [cg: +2064B] [co(128)] x16B
  __shared__ float red[4][8][2];

  int blk = blockIdx.x;
  int pt = blk & 31, b = (blk >> 5) & 15, e = blk >> 9;
  int tid = threadIdx.x, lane = tid & 63, wave = tid >> 6;
  int quad = lane >> 4, l15 = lane & 15;
  int h0 = pt * 2;
  int h_local = wave >> 1, wbase = (wave & 1) * 32;

  f32x4 acc[8][2];
#pragma unroll
  for (int mt = 0; mt < 8; ++mt)
#pragma unroll
    for (int nt = 0; nt < 2; ++nt) acc[mt][nt] = (f32x4){0.f, 0.f, 0.f, 0.f};

  bf16x8 bz;
#pragma unroll
  for (int j = 0; j < 8; ++j) bz[j] = (__bf16)0.f;

  for (int half = 0; half < 2; ++half) {
    __syncthreads();  // all waves done reading xls from previous half
    // ---- stage X: 32 segs (cg 8 x r 4) of 1KB, 8 per wave ----
#pragma unroll
    for (int s = 0; s < 8; ++s) {
      int seg = wave * 8 + s;
      int cg = seg >> 2, r = seg & 3;
      int h = h0 - 1 + r;
      char* ldst = xls + cg * 4112 + r * 1024 + lane * 16;
      if ((unsigned)h < 64u) {
        const uint4* g = (const uint4*)((const char*)xT +
            ((size_t)((b * 64 + h) * 16) + half * 8 + cg) * 1024) + lane;
        *(uint4*)ldst = *g;
      } else {
        *(uint4*)ldst = make_uint4(0u, 0u, 0u, 0u);
      }
    }
    for (int tap = 0; tap < 9; ++tap) {
      int dr = tap / 3, ds = tap % 3;
      __syncthreads();  // previous tap's wls reads complete
      // ---- stage W tap: 16 segs (cg 8 x co-blk 2) of 1KB, 4 per wave ----
#pragma unroll
      for (int s = 0; s < 4; ++s) {
        int seg = wave * 4 + s;
        int cg = seg >> 1, cb = seg & 1;
        const uint4* g = (const uint4*)((const char*)wT +
            ((size_t)(((e * 9 + tap) * 16) + half * 8 + cg) * 128 + cb * 64) * 16) + lane;
        *(uint4*)(wls + cg * 2064 + cb * 1024 + lane * 16) = *g;
      }
      __syncthreads();  // publish W (and X on first tap)
      int r_local = h_local + dr;
#pragma unroll
      for (int kc = 0; kc < 2; ++kc) {
        int cgq = kc * 4 + quad;
        bf16x8 af[8];
#pragma unroll
        for (int mt = 0; mt < 8; ++mt)
          af[mt] = *(const bf16x8*)(wls + cgq * 2064 + (mt * 16 + l15) * 16);
        bf16x8 bfr[2];
#pragma unroll
        for (int nt = 0; nt < 2; ++nt) {
          int w = wbase + nt * 16 + l15;
          int wsrc = w + ds - 1;
          bool valid = (unsigned)wsrc < 64u;
          int wc = valid ? wsrc : 0;
          bf16x8 v = *(const bf16x8*)(xls + cgq * 4112 + (r_local * 64 + wc) * 16);
          bfr[nt] = valid ? v : bz;
        }
#pragma unroll
        for (int mt = 0; mt < 8; ++mt)
#pragma unroll
          for (int nt = 0; nt < 2; ++nt)
            acc[mt][nt] = __builtin_amdgcn_mfma_f32_16x16x32_bf16(
                af[mt], bfr[nt], acc[mt][nt], 0, 0, 0);
      }
    }
  }

  // ---- epilogue: write raw ys (bf16) + partial GN stats per group ----
  int hh = h0 + h_local;
  bf16* yb = ys + (size_t)((e * 16 + b) * 128) * 4096;
#pragma unroll
  for (int mt = 0; mt < 8; ++mt) {
    float s = 0.f, ss = 0.f;
#pragma unroll
    for (int nt = 0; nt < 2; ++nt) {
      int w = wbase + nt * 16 + l15;
      int pos = hh * 64 + w;
#pragma unroll
      for (int r = 0; r < 4; ++r) {
        float v = acc[mt][nt][r];
        s += v;
        ss += v * v;
        int co = mt * 16 + quad * 4 + r;
        yb[(size_t)co * 4096 + pos] = f2bf(v);
      }
    }
#pragma unroll
    for (int off = 32; off; off >>= 1) {
      s += __shfl_down(s, off, 64);
      ss += __shfl_down(ss, off, 64);
    }
    if (lane == 0) { red[wave][mt][0] = s; red[wave][mt][1] = ss; }
  }
  __syncthreads();
  if (tid < 16) {
    int g = tid >> 1, which = tid & 1;
    float t = red[0][g][which] + red[1][g][which] + red[2][g][which] + red[3][g][which];
    atomicAdd(&statsE[((e * 16 + b) * 8 + g) * 2 + which], t);
  }
}

// ---------------- finalize expert GN stats ---------------------------------
__global__ void finalize_stats(float* __restrict__ st) {
  int i = blockIdx.x * 256 + threadIdx.x;  // 1024 = (e,b,g)
  if (i >= 1024) return;
  float S = st[i * 2], SS = st[i * 2 + 1];
  float mean = S * (1.f / 65536.f);
  float var = SS * (1.f / 65536.f) - mean * mean;
  st[i * 2] = mean;
  st[i * 2 + 1] = rsqrtf(var + 1e-5f);
}

// ---------------- combine: x + sum_e silu(gn(ys_e)) * wt_e -----------------
__global__ void combine_kernel(const float* __restrict__ x, const bf16* __restrict__ ys,
                               const float* __restrict__ st, const float* __restrict__ gns,
                               const float* __restrict__ gnb, const float* __restrict__ wts,
                               float* __restrict__ combined) {
  const int total = B_ * COUT_ * HW_;
  for (int idx = blockIdx.x * blockDim.x + threadIdx.x; idx < total;
       idx += gridDim.x * blockDim.x) {
    int pos = idx & 4095, co = (idx >> 12) & 127, b = idx >> 19;
    int g = co >> 4;
    int h = pos >> 6, w = pos & 63;
    int pid = (h >> 4) * 4 + (w >> 4);
    float v = x[idx];
#pragma unroll
    for (int e = 0; e < E_; ++e) {
      float mean = st[((e * 16 + b) * 8 + g) * 2];
      float rstd = st[((e * 16 + b) * 8 + g) * 2 + 1];
      float y = bf2f(ys[((size_t)((e * 16 + b) * 128 + co) << 12) + pos]);
      float t = (y - mean) * rstd * gns[e * 128 + co] + gnb[e * 128 + co];
      v += siluf(t) * wts[pid * 8 + e];
    }
    combined[idx] = v;
  }
}

// ---------------- pw1: 1x1 conv 128->512 + partial GN stats ----------------
__global__ __launch_bounds__(256, 2) void pw1_kernel(
    const float* __restrict__ combined, const float* __restrict__ w_pw1,
    bf16* __restrict__ h1_raw, float* __restrict__ stats1) {
  __shared__ float red[8];
  int blk = blockIdx.x;
  int ot = blk & 63, b = blk >> 6;
  int o0 = ot * 8;
  int t = threadIdx.x;
  float acc[8][16];
#pragma unroll
  for (int k = 0; k < 8; ++k)
#pragma unroll
    for (int j = 0; j < 16; ++j) acc[k][j] = 0.f;
  const float* cbase = combined + (size_t)b * COUT_ * HW_;
  for (int c = 0; c < COUT_; ++c) {
    float wv[8];
#pragma unroll
    for (int k = 0; k < 8; ++k) wv[k] = w_pw1[(o0 + k) * COUT_ + c];
    const float* cp = cbase + c * HW_;
#pragma unroll
    for (int j = 0; j < 16; ++j) {
      float in = cp[t + j * 256];
#pragma unroll
      for (int k = 0; k < 8; ++k) acc[k][j] = fmaf(in, wv[k], acc[k][j]);
    }
  }
  float s = 0.f, ss = 0.f;
#pragma unroll
  for (int k = 0; k < 8; ++k)
#pragma unroll
    for (int j = 0; j < 16; ++j) {
      float v = acc[k][j];
      s += v; ss += v * v;
      h1_raw[(size_t)(b * HC_ + o0 + k) * HW_ + t + j * 256] = f2bf(v);
    }
#pragma unroll
  for (int off = 32; off > 0; off >>= 1) {
    s += __shfl_down(s, off, 64);
    ss += __shfl_down(ss, off, 64);
  }
  int wave = t >> 6;
  if ((t & 63) == 0) { red[wave * 2] = s; red[wave * 2 + 1] = ss; }
  __syncthreads();
  if (t == 0) {
    float S = red[0] + red[2] + red[4] + red[6];
    float SS = red[1] + red[3] + red[5] + red[7];
    int bg = b * 8 + (ot >> 3);
    atomicAdd(&stats1[bg * 2], S);
    atomicAdd(&stats1[bg * 2 + 1], SS);
  }
}

// ---------------- normalize+SiLU for h1/h2 ---------------------------------
__global__ void norm_kernel(const bf16* __restrict__ raw, const float* __restrict__ stats,
                            const float* __restrict__ gs, const float* __restrict__ gb,
                            bf16* __restrict__ outb) {
  const int total = B_ * HC_ * HW_;
  for (int idx = blockIdx.x * blockDim.x + threadIdx.x; idx < total; idx += gridDim.x * blockDim.x) {
    int c = (idx >> 12) & 511;
    int b = idx >> 21;
    int bg = b * 8 + (c >> 6);
    float S = stats[bg * 2], SS = stats[bg * 2 + 1];
    float mean = S * (1.f / 262144.f);
    float var = SS * (1.f / 262144.f) - mean * mean;
    float rstd = rsqrtf(var + 1e-5f);
    float v = bf2f(raw[idx]);
    v = (v - mean) * rstd * gs[c] + gb[c];
    outb[idx] = f2bf(siluf(v));
  }
}

// ---------------- depthwise 3x3 + partial GN stats -------------------------
__global__ __launch_bounds__(256) void dw_kernel(
    const bf16* __restrict__ h1n, const float* __restrict__ w_dw,
    bf16* __restrict__ h2_raw, float* __restrict__ stats2) {
  __shared__ float red[8];
  int blk = blockIdx.x;
  int hc = blk & 511, b = blk >> 9;
  int t = threadIdx.x;
  const bf16* in = h1n + (size_t)blk * HW_;
  bf16* outp = h2_raw + (size_t)blk * HW_;
  float wv[9];
#pragma unroll
  for (int i = 0; i < 9; ++i) wv[i] = w_dw[hc * 9 + i];
  float s = 0.f, ss = 0.f;
  for (int j = 0; j < 16; ++j) {
    int pos = t + j * 256;
    int h = pos >> 6, w = pos & 63;
    float acc = 0.f;
#pragma unroll
    for (int r = 0; r < 3; ++r) {
      int hh = h + r - 1;
      if ((unsigned)hh < 64u) {
#pragma unroll
        for (int s2 = 0; s2 < 3; ++s2) {
          int ww = w + s2 - 1;
          if ((unsigned)ww < 64u)
            acc = fmaf(bf2f(in[hh * 64 + ww]), wv[r * 3 + s2], acc);
        }
      }
    }
    outp[pos] = f2bf(acc);
    s += acc; ss += acc * acc;
  }
#pragma unroll
  for (int off = 32; off > 0; off >>= 1) {
    s += __shfl_down(s, off, 64);
    ss += __shfl_down(ss, off, 64);
  }
  int wave = t >> 6;
  if ((t & 63) == 0) { red[wave * 2] = s; red[wave * 2 + 1] = ss; }
  __syncthreads();
  if (t == 0) {
    float S = red[0] + red[2] + red[4] + red[6];
    float SS = red[1] + red[3] + red[5] + red[7];
    int bg = b * 8 + (hc >> 6);
    atomicAdd(&stats2[bg * 2], S);
    atomicAdd(&stats2[bg * 2 + 1], SS);
  }
}

// ---------------- pw2: 1x1 stride-2 conv 512->128 + partial GN stats -------
__global__ __launch_bounds__(256) void pw2_kernel(
    const bf16* __restrict__ h2n, const float* __restrict__ w_pw2,
    float* __restrict__ h3_raw, float* __restrict__ stats3) {
  __shared__ float red[8];
  int blk = blockIdx.x;
  int ot = blk & 31, b = blk >> 5;
  int o0 = ot * 4;
  int t = threadIdx.x;
  float acc[4][4];
#pragma unroll
  for (int k = 0; k < 4; ++k)
#pragma unroll
    for (int j = 0; j < 4; ++j) acc[k][j] = 0.f;
  const bf16* ib = h2n + (size_t)b * HC_ * HW_;
  for (int c = 0; c < HC_; ++c) {
    float wv[4];
#pragma unroll
    for (int k = 0; k < 4; ++k) wv[k] = w_pw2[(o0 + k) * HC_ + c];
    const bf16* cp = ib + c * HW_;
#pragma unroll
    for (int j = 0; j < 4; ++j) {
      int pos = t + j * 256;
      int h2 = pos >> 5, w2 = pos & 31;
      float in = bf2f(cp[h2 * 128 + w2 * 2]);
#pragma unroll
      for (int k = 0; k < 4; ++k) acc[k][j] = fmaf(in, wv[k], acc[k][j]);
    }
  }
  float s = 0.f, ss = 0.f;
#pragma unroll
  for (int k = 0; k < 4; ++k)
#pragma unroll
    for (int j = 0; j < 4; ++j) {
      int pos = t + j * 256;
      float v = acc[k][j];
      s += v; ss += v * v;
      h3_raw[(size_t)(b * COUT_ + o0 + k) * 1024 + pos] = v;
    }
#pragma unroll
  for (int off = 32; off > 0; off >>= 1) {
    s += __shfl_down(s, off, 64);
    ss += __shfl_down(ss, off, 64);
  }
  int wave = t >> 6;
  if ((t & 63) == 0) { red[wave * 2] = s; red[wave * 2 + 1] = ss; }
  __syncthreads();
  if (t == 0) {
    float S = red[0] + red[2] + red[4] + red[6];
    float SS = red[1] + red[3] + red[5] + red[7];
    int bg = b * 8 + (o0 >> 4);
    atomicAdd(&stats3[bg * 2], S);
    atomicAdd(&stats3[bg * 2 + 1], SS);
  }
}

// ---------------- final GN+SiLU -> d_out (fp32) ----------------------------
__global__ void out_kernel(const float* __restrict__ h3, const float* __restrict__ stats,
                           const float* __restrict__ gs, const float* __restrict__ gb,
                           float* __restrict__ out) {
  const int total = B_ * COUT_ * 1024;
  for (int idx = blockIdx.x * blockDim.x + threadIdx.x; idx < total; idx += gridDim.x * blockDim.x) {
    int c = (idx >> 10) & 127;
    int b = idx >> 17;
    int bg = b * 8 + (c >> 4);
    float S = stats[bg * 2], SS = stats[bg * 2 + 1];
    float mean = S * (1.f / 16384.f);
    float var = SS * (1.f / 16384.f) - mean * mean;
    float rstd = rsqrtf(var + 1e-5f);
    float v = (h3[idx] - mean) * rstd * gs[c] + gb[c];
    out[idx] = siluf(v);
  }
}

extern "C" void kernel_launch(void* const* d_in, const int* in_sizes, int n_in,
                              void* d_out, int out_size, void* d_ws, size_t ws_size,
                              hipStream_t stream) {
  const float* x = (const float*)d_in[0];
  const float* w_exp = (const float*)d_in[1];
  const float* gn_exp_s = (const float*)d_in[2];
  const float* gn_exp_b = (const float*)d_in[3];
  const float* w1 = (const float*)d_in[4];
  const float* b1 = (const float*)d_in[5];
  const float* w2 = (const float*)d_in[6];
  const float* b2 = (const float*)d_in[7];
  const float* w_pw1 = (const float*)d_in[8];
  const float* gn1_s = (const float*)d_in[9];
  const float* gn1_b = (const float*)d_in[10];
  const float* w_dw = (const float*)d_in[11];
  const float* gn2_s = (const float*)d_in[12];
  const float* gn2_b = (const float*)d_in[13];
  const float* w_pw2 = (const float*)d_in[14];
  const float* gn3_s = (const float*)d_in[15];
  const float* gn3_b = (const float*)d_in[16];

  char* ws = (char*)d_ws;
  const size_t COMBINED_OFF = 16384;
  const size_t COMBINED_BYTES = (size_t)B_ * COUT_ * HW_ * 4;     // 33.5 MB
  const size_t SLOT_BYTES = (size_t)B_ * HC_ * HW_ * 2;           // 67.1 MB
  const size_t NEEDED = COMBINED_OFF + COMBINED_BYTES + 2 * SLOT_BYTES;
  if (ws_size < NEEDED) return;

  float* wts = (float*)ws;
  float* stats1 = (float*)(ws + 1024);
  float* stats2 = (float*)(ws + 2048);
  float* stats3 = (float*)(ws + 3072);
  float* statsE = (float*)(ws + 4096);
  float* combined = (float*)(ws + COMBINED_OFF);
  bf16* xT = (bf16*)(ws + COMBINED_OFF);                 // aliases combined (dead after conv)
  bf16* wT = (bf16*)(ws + COMBINED_OFF + 17039360);      // 16.25MB past xT, inside combined
  char* slotA = ws + COMBINED_OFF + COMBINED_BYTES;
  char* slotB = slotA + SLOT_BYTES;
  bf16* ys = (bf16*)slotA;       // 134.2 MB spans slotA+slotB, dead after combine
  bf16* h1_raw = (bf16*)slotA;
  bf16* h1n = (bf16*)slotB;
  bf16* h2_raw = (bf16*)slotA;
  bf16* h2n = (bf16*)slotB;
  float* h3_raw = combined;

  hipMemsetAsync(ws, 0, 16384, stream);  // zero all stats buffers
  gate_kernel<<<1, 64, 0, stream>>>(w1, b1, w2, b2, wts);
  xt_kernel<<<B_ * 64, 256, 0, stream>>>(x, xT);
  wt_kernel<<<4608, 256, 0, stream>>>(w_exp, wT);
  conv_mfma<<<E_ * B_ * 32, 256, 0, stream>>>(xT, wT, statsE, ys);
  finalize_stats<<<4, 256, 0, stream>>>(statsE);
  combine_kernel<<<2048, 256, 0, stream>>>(x, ys, statsE, gn_exp_s, gn_exp_b, wts, combined);
  pw1_kernel<<<B_ * 64, 256, 0, stream>>>(combined, w_pw1, h1_raw, stats1);
  norm_kernel<<<2048, 256, 0, stream>>>(h1_raw, stats1, gn1_s, gn1_b, h1n);
  dw_kernel<<<B_ * HC_, 256, 0, stream>>>(h1n, w_dw, h2_raw, stats2);
  norm_kernel<<<2048, 256, 0, stream>>>(h2_raw, stats2, gn2_s, gn2_b, h2n);
  pw2_kernel<<<B_ * 32, 256, 0, stream>>>(h2n, w_pw2, h3_raw, stats3);
  out_kernel<<<1024, 256, 0, stream>>>(h3_raw, stats3, gn3_s, gn3_b, (float*)d_out);
}

// Round 4
// 591.791 us; speedup vs baseline: 5.7220x; 1.5470x over previous
//
#include <hip/hip_runtime.h>
#include <hip/hip_bf16.h>

// ---------------------------------------------------------------------------
// PCELayer R4 = R3 with pw1_mfma output-write indexing fixed
// (r=id>>4, q=id&15: 128 rows x 256B, 16B per id; R3's r=id>>1 wrote OOB).
//  conv_mfma v2: 4-row blocks, wave = 1 row x 64 w (8mt x 4nt), bank-aligned
//    LDS strides (multiples of 128 B).
//  Back half: combine -> bf16 channels-last; pw1 = MFMA GEMM (+GN1 stats);
//    dw fuses GN1+SiLU on read, emits compact stride-2 output (+GN2 stats);
//    norm2 in-place; pw2 = MFMA GEMM (+GN3 stats); out kernel unchanged.
// Workspace (153.6 MB):
//   head 16K: wts/stats1/stats2/stats3/statsE
//   wp1T 128K | wp2T 128K
//   XT 16.8M (-> combined_cl after conv)
//   WT 2.4M
//   YS 134.2M (-> h1cl 67M | h2cl 16.8M | h3 8.4M after combine)
// ---------------------------------------------------------------------------

#define B_ 16
#define CIN_ 128
#define COUT_ 128
#define H_ 64
#define W_ 64
#define HW_ 4096
#define E_ 8
#define FF_ 8
#define GC_ 32
#define HID_ 64
#define HC_ 512

typedef __hip_bfloat16 bf16;
typedef __bf16 bf16x8 __attribute__((ext_vector_type(8)));
typedef float f32x4 __attribute__((ext_vector_type(4)));

__device__ __forceinline__ float siluf(float v) { return v / (1.f + __expf(-v)); }
__device__ __forceinline__ float bf2f(bf16 v) { return __bfloat162float(v); }
__device__ __forceinline__ bf16 f2bf(float v) { return __float2bfloat16(v); }

// ---------------- router gate ----------------------------------------------
__global__ void gate_kernel(const float* __restrict__ w1, const float* __restrict__ b1,
                            const float* __restrict__ w2, const float* __restrict__ b2,
                            float* __restrict__ wts) {
  int p = threadIdx.x;
  if (p >= 16) return;
  int i = p >> 2, j = p & 3;
  float cy = (i + 0.5f) * 0.25f;
  float cx = (j + 0.5f) * 0.25f;
  float feats[GC_];
#pragma unroll
  for (int f = 0; f < FF_; ++f) {
    float fr = 3.14159265358979f * (float)(1 << f);
    float ay = cy * fr, ax = cx * fr;
    feats[f] = sinf(ay);
    feats[FF_ + f] = cosf(ay);
    feats[2 * FF_ + f] = sinf(ax);
    feats[3 * FF_ + f] = cosf(ax);
  }
  float hid[HID_];
  for (int k = 0; k < HID_; ++k) {
    float a = b1[k];
#pragma unroll
    for (int m = 0; m < GC_; ++m) a = fmaf(feats[m], w1[m * HID_ + k], a);
    hid[k] = siluf(a);
  }
  float lg[E_];
  float mx = -1e30f;
#pragma unroll
  for (int e = 0; e < E_; ++e) {
    float a = b2[e];
    for (int k = 0; k < HID_; ++k) a = fmaf(hid[k], w2[k * E_ + e], a);
    lg[e] = a;
    mx = fmaxf(mx, a);
  }
  float s = 0.f;
#pragma unroll
  for (int e = 0; e < E_; ++e) { lg[e] = __expf(lg[e] - mx); s += lg[e]; }
  float inv = 1.f / s;
#pragma unroll
  for (int e = 0; e < E_; ++e) wts[p * E_ + e] = lg[e] * inv;
}

// ---------------- x -> channels-last bf16 ----------------------------------
__global__ __launch_bounds__(256) void xt_kernel(const float* __restrict__ x,
                                                 bf16* __restrict__ xT) {
  __shared__ float t[128][65];
  int b = blockIdx.x >> 6, h = blockIdx.x & 63;
  int tid = threadIdx.x;
  int w = tid & 63, c4 = tid >> 6;
  const float* xb = x + ((size_t)(b * 128) * 64 + h) * 64;
#pragma unroll 4
  for (int rep = 0; rep < 32; ++rep) {
    int ci = rep * 4 + c4;
    t[ci][w] = xb[(size_t)ci * HW_ + w];
  }
  __syncthreads();
  bf16* dst = xT + (size_t)(b * 64 + h) * 8192;
#pragma unroll 4
  for (int rep = 0; rep < 32; ++rep) {
    int o = rep * 256 + tid;
    int cg = o >> 9, w2 = (o >> 3) & 63, lo = o & 7;
    dst[o] = f2bf(t[cg * 8 + lo][w2]);
  }
}

// ---------------- w_exp -> wT bf16 -----------------------------------------
__global__ void wt_kernel(const float* __restrict__ w_exp, bf16* __restrict__ wT) {
  int idx = blockIdx.x * 256 + threadIdx.x;
  if (idx >= 1179648) return;
  int lo = idx & 7;
  int co = (idx >> 3) & 127;
  int cg = (idx >> 10) & 15;
  int rest = idx >> 14;
  int tap = rest % 9, e = rest / 9;
  int ci = cg * 8 + lo;
  wT[idx] = f2bf(w_exp[(((size_t)(e * 128 + co) * 128 + ci) * 9) + tap]);
}

// ---------------- pw weights fp32 -> bf16 ----------------------------------
__global__ void wpT_kernel(const float* __restrict__ w_pw1, const float* __restrict__ w_pw2,
                           bf16* __restrict__ wp1T, bf16* __restrict__ wp2T) {
  int idx = blockIdx.x * 256 + threadIdx.x;
  if (idx < 65536) wp1T[idx] = f2bf(w_pw1[idx]);
  else if (idx < 131072) wp2T[idx - 65536] = f2bf(w_pw2[idx - 65536]);
}

// ---------------- expert conv via MFMA (v2) --------------------------------
__global__ __launch_bounds__(256, 2) void conv_mfma(
    const bf16* __restrict__ xT, const bf16* __restrict__ wT,
    float* __restrict__ statsE, bf16* __restrict__ ys) {
  __shared__ __align__(16) char xls[8 * 6144];   // [cg(8)][r(6)][w(64)]x16B = 48K
  __shared__ __align__(16) char wls[8 * 2048];   // [cg(8)][co(128)]x16B = 16K
  __shared__ float red[4][8][2];

  int blk = blockIdx.x;
  int rt = blk & 15, b = (blk >> 4) & 15, e = blk >> 8;
  int tid = threadIdx.x, lane = tid & 63, wave = tid >> 6;
  int quad = lane >> 4, l15 = lane & 15;
  int h0 = rt * 4;
  int h_local = wave;

  f32x4 acc[8][4];
#pragma unroll
  for (int mt = 0; mt < 8; ++mt)
#pragma unroll
    for (int nt = 0; nt < 4; ++nt) acc[mt][nt] = (f32x4){0.f, 0.f, 0.f, 0.f};

  bf16x8 bz;
#pragma unroll
  for (int j = 0; j < 8; ++j) bz[j] = (__bf16)0.f;

  for (int half = 0; half < 2; ++half) {
    __syncthreads();
#pragma unroll
    for (int s = 0; s < 12; ++s) {
      int seg = wave * 12 + s;
      int cg = seg / 6, r = seg % 6;
      int h = h0 - 1 + r;
      char* ldst = xls + cg * 6144 + r * 1024 + lane * 16;
      if ((unsigned)h < 64u) {
        const uint4* g = (const uint4*)((const char*)xT +
            ((size_t)((b * 64 + h) * 16) + half * 8 + cg) * 1024) + lane;
        *(uint4*)ldst = *g;
      } else {
        *(uint4*)ldst = make_uint4(0u, 0u, 0u, 0u);
      }
    }
    for (int tap = 0; tap < 9; ++tap) {
      int dr = tap / 3, ds = tap % 3;
      __syncthreads();
#pragma unroll
      for (int s = 0; s < 4; ++s) {
        int seg = wave * 4 + s;
        int cg = seg >> 1, cb = seg & 1;
        const uint4* g = (const uint4*)((const char*)wT +
            ((size_t)(((e * 9 + tap) * 16) + half * 8 + cg) * 128 + cb * 64) * 16) + lane;
        *(uint4*)(wls + cg * 2048 + cb * 1024 + lane * 16) = *g;
      }
      __syncthreads();
      int r_local = h_local + dr;
#pragma unroll
      for (int kc = 0; kc < 2; ++kc) {
        int cgq = kc * 4 + quad;
        bf16x8 af[8];
#pragma unroll
        for (int mt = 0; mt < 8; ++mt)
          af[mt] = *(const bf16x8*)(wls + cgq * 2048 + (mt * 16 + l15) * 16);
        bf16x8 bfr[4];
#pragma unroll
        for (int nt = 0; nt < 4; ++nt) {
          int w = nt * 16 + l15;
          int wsrc = w + ds - 1;
          bool valid = (unsigned)wsrc < 64u;
          int wc = valid ? wsrc : 0;
          bf16x8 v = *(const bf16x8*)(xls + cgq * 6144 + (r_local * 64 + wc) * 16);
          bfr[nt] = valid ? v : bz;
        }
#pragma unroll
        for (int mt = 0; mt < 8; ++mt)
#pragma unroll
          for (int nt = 0; nt < 4; ++nt)
            acc[mt][nt] = __builtin_amdgcn_mfma_f32_16x16x32_bf16(
                af[mt], bfr[nt], acc[mt][nt], 0, 0, 0);
      }
    }
  }

  int hh = h0 + h_local;
  bf16* yb = ys + (size_t)((e * 16 + b) * 128) * 4096;
#pragma unroll
  for (int mt = 0; mt < 8; ++mt) {
    float s = 0.f, ss = 0.f;
#pragma unroll
    for (int nt = 0; nt < 4; ++nt) {
      int w = nt * 16 + l15;
      int pos = hh * 64 + w;
#pragma unroll
      for (int r = 0; r < 4; ++r) {
        float v = acc[mt][nt][r];
        s += v;
        ss += v * v;
        int co = mt * 16 + quad * 4 + r;
        yb[(size_t)co * 4096 + pos] = f2bf(v);
      }
    }
#pragma unroll
    for (int off = 32; off; off >>= 1) {
      s += __shfl_down(s, off, 64);
      ss += __shfl_down(ss, off, 64);
    }
    if (lane == 0) { red[wave][mt][0] = s; red[wave][mt][1] = ss; }
  }
  __syncthreads();
  if (tid < 16) {
    int g = tid >> 1, which = tid & 1;
    float t = red[0][g][which] + red[1][g][which] + red[2][g][which] + red[3][g][which];
    atomicAdd(&statsE[((e * 16 + b) * 8 + g) * 2 + which], t);
  }
}

// ---------------- generic stats finalize: raw S/SS -> mean/rstd ------------
__global__ void finalize_stats(float* __restrict__ st, int n, float inv) {
  int i = blockIdx.x * 256 + threadIdx.x;
  if (i >= n) return;
  float S = st[i * 2], SS = st[i * 2 + 1];
  float mean = S * inv;
  float var = SS * inv - mean * mean;
  st[i * 2] = mean;
  st[i * 2 + 1] = rsqrtf(var + 1e-5f);
}

// ---------------- combine -> bf16 channels-last ----------------------------
__global__ __launch_bounds__(256) void combine_cl(
    const float* __restrict__ x, const bf16* __restrict__ ys,
    const float* __restrict__ st, const float* __restrict__ gns,
    const float* __restrict__ gnb, const float* __restrict__ wts,
    bf16* __restrict__ ccl) {
  __shared__ bf16 tile[64][132];
  int b = blockIdx.x >> 6, h = blockIdx.x & 63;
  int t = threadIdx.x;
  int w32 = t & 31, coq = t >> 5;
  float m_[8], r_[8];
#pragma unroll
  for (int e = 0; e < 8; ++e) {
    m_[e] = st[((e * 16 + b) * 8 + coq) * 2];
    r_[e] = st[((e * 16 + b) * 8 + coq) * 2 + 1];
  }
#pragma unroll
  for (int wt2 = 0; wt2 < 2; ++wt2) {
    int w = wt2 * 32 + w32;
    int pid = (h >> 4) * 4 + (w >> 4);
    int pos = h * 64 + w;
    float wt_[8];
#pragma unroll
    for (int e = 0; e < 8; ++e) wt_[e] = wts[pid * 8 + e];
    for (int coi = 0; coi < 16; ++coi) {
      int co = coq * 16 + coi;
      float v = x[((size_t)(b * 128 + co) << 12) + pos];
#pragma unroll
      for (int e = 0; e < 8; ++e) {
        float y = bf2f(ys[((size_t)((e * 16 + b) * 128 + co) << 12) + pos]);
        float yn = (y - m_[e]) * r_[e] * gns[e * 128 + co] + gnb[e * 128 + co];
        v += siluf(yn) * wt_[e];
      }
      tile[w][co] = f2bf(v);
    }
  }
  __syncthreads();
  int row = t >> 2, q = t & 3;
  char* dst = (char*)ccl + ((size_t)(b * 4096 + h * 64 + row)) * 256 + q * 64;
  const char* src = (const char*)&tile[row][0] + q * 64;
#pragma unroll
  for (int i = 0; i < 4; ++i)
    *(uint4*)(dst + i * 16) = *(const uint4*)(src + i * 16);
}

// ---------------- pw1 MFMA: h1[hc=512][n=65536] = w[hc][ci] @ ccl[n][ci] ---
__global__ __launch_bounds__(256) void pw1_mfma(
    const bf16* __restrict__ ccl, const bf16* __restrict__ wp1T,
    bf16* __restrict__ h1cl, float* __restrict__ stats1) {
  __shared__ __align__(16) char ls[65536];  // als 32K | bls 32K ; reused as tile
  __shared__ float red[4][2][2];
  char* als = ls;
  char* bls = ls + 32768;
  int blk = blockIdx.x;
  int ntile = blk & 511, mtile = blk >> 9;
  int n0 = ntile * 128, m0 = mtile * 128;
  int t = threadIdx.x, lane = t & 63, wave = t >> 6;
  int quad = lane >> 4, l15 = lane & 15;
  int b = n0 >> 12;

#pragma unroll
  for (int i = 0; i < 8; ++i) {
    int id = t + 256 * i;
    int r = id >> 4, c = id & 15;
    *(uint4*)(als + c * 2048 + r * 16) =
        *(const uint4*)((const char*)wp1T + (size_t)(m0 + r) * 256 + c * 16);
    *(uint4*)(bls + c * 2048 + r * 16) =
        *(const uint4*)((const char*)ccl + (size_t)(n0 + r) * 256 + c * 16);
  }
  __syncthreads();

  f32x4 acc[8][2];
#pragma unroll
  for (int mt = 0; mt < 8; ++mt)
#pragma unroll
    for (int nt = 0; nt < 2; ++nt) acc[mt][nt] = (f32x4){0.f, 0.f, 0.f, 0.f};

#pragma unroll
  for (int kc = 0; kc < 4; ++kc) {
    int cgq = kc * 4 + quad;
    bf16x8 af[8];
#pragma unroll
    for (int mt = 0; mt < 8; ++mt)
      af[mt] = *(const bf16x8*)(als + cgq * 2048 + (mt * 16 + l15) * 16);
    bf16x8 bfr[2];
#pragma unroll
    for (int nt = 0; nt < 2; ++nt)
      bfr[nt] = *(const bf16x8*)(bls + cgq * 2048 + (wave * 32 + nt * 16 + l15) * 16);
#pragma unroll
    for (int mt = 0; mt < 8; ++mt)
#pragma unroll
      for (int nt = 0; nt < 2; ++nt)
        acc[mt][nt] = __builtin_amdgcn_mfma_f32_16x16x32_bf16(
            af[mt], bfr[nt], acc[mt][nt], 0, 0, 0);
  }

  __syncthreads();  // everyone done with als/bls
  float s[2] = {0.f, 0.f}, ss[2] = {0.f, 0.f};
  bf16* tile = (bf16*)ls;  // row stride 132 elems = 264 B
#pragma unroll
  for (int mt = 0; mt < 8; ++mt) {
    int gi = mt >> 2;
#pragma unroll
    for (int nt = 0; nt < 2; ++nt) {
      int n = wave * 32 + nt * 16 + l15;
#pragma unroll
      for (int r = 0; r < 4; ++r) {
        float v = acc[mt][nt][r];
        s[gi] += v;
        ss[gi] += v * v;
        tile[n * 132 + mt * 16 + quad * 4 + r] = f2bf(v);
      }
    }
  }
#pragma unroll
  for (int gi = 0; gi < 2; ++gi) {
#pragma unroll
    for (int off = 32; off; off >>= 1) {
      s[gi] += __shfl_down(s[gi], off, 64);
      ss[gi] += __shfl_down(ss[gi], off, 64);
    }
  }
  if (lane == 0) {
    red[wave][0][0] = s[0]; red[wave][0][1] = ss[0];
    red[wave][1][0] = s[1]; red[wave][1][1] = ss[1];
  }
  __syncthreads();
  if (t < 4) {
    int gi = t >> 1, which = t & 1;
    float v = red[0][gi][which] + red[1][gi][which] + red[2][gi][which] + red[3][gi][which];
    atomicAdd(&stats1[(b * 8 + mtile * 2 + gi) * 2 + which], v);
  }
  // coalesced global write: 128 rows x 256 B (FIXED: r=id>>4, q=id&15)
#pragma unroll
  for (int i = 0; i < 8; ++i) {
    int id = t + 256 * i;             // 0..2047
    int r = id >> 4, q = id & 15;     // 128 rows x 16 chunks of 16B
    char* dst = (char*)h1cl + (size_t)(n0 + r) * 1024 + m0 * 2 + q * 16;
    const char* src = (const char*)tile + r * 264 + q * 16;
    *(uint4*)dst = *(const uint4*)src;
  }
}

// ---------------- dw3x3, fused GN1+SiLU on read, compact stride-2 out ------
__global__ __launch_bounds__(256) void dw_cl(
    const bf16* __restrict__ h1cl, const float* __restrict__ w_dw,
    const float* __restrict__ st1, const float* __restrict__ gs,
    const float* __restrict__ gb, bf16* __restrict__ h2cl,
    float* __restrict__ stats2) {
  __shared__ float lds_w[576];
  __shared__ float red2[4][2];
  int blk = blockIdx.x;
  int hcb = blk & 7, h = (blk >> 3) & 63, b = blk >> 9;
  int t = threadIdx.x;
  int w = t & 63, hcq = t >> 6;
  int hc0 = hcb * 64 + hcq * 16;
  for (int i = t; i < 576; i += 256) lds_w[i] = w_dw[hcb * 576 + i];
  float mean = st1[(b * 8 + hcb) * 2], rstd = st1[(b * 8 + hcb) * 2 + 1];
  float scale[16], shift[16];
#pragma unroll
  for (int j = 0; j < 16; ++j) {
    float g = gs[hc0 + j];
    scale[j] = rstd * g;
    shift[j] = gb[hc0 + j] - mean * rstd * g;
  }
  __syncthreads();
  float acc[16];
#pragma unroll
  for (int j = 0; j < 16; ++j) acc[j] = 0.f;
  const char* base = (const char*)h1cl + (size_t)b * 4096 * 1024 + hc0 * 2;
#pragma unroll
  for (int dr = 0; dr < 3; ++dr) {
    int hh = h + dr - 1;
    if ((unsigned)hh >= 64u) continue;
#pragma unroll
    for (int ds = 0; ds < 3; ++ds) {
      int ww = w + ds - 1;
      if ((unsigned)ww >= 64u) continue;
      const char* p = base + (size_t)(hh * 64 + ww) * 1024;
      uint4 a0 = *(const uint4*)p;
      uint4 a1 = *(const uint4*)(p + 16);
      const bf16* pv = (const bf16*)&a0;
      const bf16* pv1 = (const bf16*)&a1;
      int hcl = hcq * 16;
#pragma unroll
      for (int j = 0; j < 8; ++j) {
        float v = bf2f(pv[j]) * scale[j] + shift[j];
        acc[j] = fmaf(siluf(v), lds_w[(hcl + j) * 9 + dr * 3 + ds], acc[j]);
      }
#pragma unroll
      for (int j = 0; j < 8; ++j) {
        float v = bf2f(pv1[j]) * scale[8 + j] + shift[8 + j];
        acc[8 + j] = fmaf(siluf(v), lds_w[(hcl + 8 + j) * 9 + dr * 3 + ds], acc[8 + j]);
      }
    }
  }
  float s = 0.f, ssum = 0.f;
#pragma unroll
  for (int j = 0; j < 16; ++j) { s += acc[j]; ssum += acc[j] * acc[j]; }
#pragma unroll
  for (int off = 32; off; off >>= 1) {
    s += __shfl_down(s, off, 64);
    ssum += __shfl_down(ssum, off, 64);
  }
  int wave = t >> 6;
  if ((t & 63) == 0) { red2[wave][0] = s; red2[wave][1] = ssum; }
  __syncthreads();
  if (t < 2) {
    float v = red2[0][t] + red2[1][t] + red2[2][t] + red2[3][t];
    atomicAdd(&stats2[(b * 8 + hcb) * 2 + t], v);
  }
  if (!(h & 1) && !(w & 1)) {
    int pos2 = (h >> 1) * 32 + (w >> 1);
    bf16 tmp[16];
#pragma unroll
    for (int j = 0; j < 16; ++j) tmp[j] = f2bf(acc[j]);
    char* dst = (char*)h2cl + ((size_t)(b * 1024 + pos2) * 512 + hc0) * 2;
    *(uint4*)dst = *(const uint4*)tmp;
    *(uint4*)(dst + 16) = *(const uint4*)(tmp + 8);
  }
}

// ---------------- norm2 in-place on compact h2cl ---------------------------
__global__ void norm2_kernel(bf16* __restrict__ h2, const float* __restrict__ st2,
                             const float* __restrict__ gs, const float* __restrict__ gb) {
  int tg = blockIdx.x * 256 + threadIdx.x;
  int e8 = tg * 8;
  int hc0 = e8 & 511;
  int rest = e8 >> 9;
  int bq = rest >> 10;
  int g = hc0 >> 6;
  float mean = st2[(bq * 8 + g) * 2], rstd = st2[(bq * 8 + g) * 2 + 1];
  uint4 v = *(const uint4*)((const char*)h2 + (size_t)tg * 16);
  bf16* pv = (bf16*)&v;
  bf16 outv[8];
#pragma unroll
  for (int j = 0; j < 8; ++j) {
    float x = bf2f(pv[j]);
    x = (x - mean) * rstd * gs[hc0 + j] + gb[hc0 + j];
    outv[j] = f2bf(siluf(x));
  }
  *(uint4*)((char*)h2 + (size_t)tg * 16) = *(const uint4*)outv;
}

// ---------------- pw2 MFMA: h3[co=128][n=16384] = w[co][hc] @ h2n[n][hc] ---
__global__ __launch_bounds__(256) void pw2_mfma(
    const bf16* __restrict__ h2n, const bf16* __restrict__ wp2T,
    float* __restrict__ h3, float* __restrict__ stats3) {
  __shared__ __align__(16) char als[2][8192];
  __shared__ __align__(16) char bls[2][4096];
  __shared__ float red[4][8][2];
  int blk = blockIdx.x;
  int n0 = blk * 64;
  int b = n0 >> 10, posb = n0 & 1023;
  int t = threadIdx.x, lane = t & 63, wave = t >> 6;
  int quad = lane >> 4, l15 = lane & 15;
  int wbase = wave * 16;

  f32x4 acc[8];
#pragma unroll
  for (int mt = 0; mt < 8; ++mt) acc[mt] = (f32x4){0.f, 0.f, 0.f, 0.f};

  {
#pragma unroll
    for (int i = 0; i < 2; ++i) {
      int id = t + 256 * i;
      int c4 = id >> 7, r = id & 127;
      *(uint4*)(als[0] + c4 * 2048 + r * 16) =
          *(const uint4*)((const char*)wp2T + (size_t)r * 1024 + c4 * 16);
    }
    int c4 = t >> 6, r = t & 63;
    *(uint4*)(bls[0] + c4 * 1024 + r * 16) =
        *(const uint4*)((const char*)h2n + (size_t)(n0 + r) * 1024 + c4 * 16);
  }
  for (int kc = 0; kc < 16; ++kc) {
    __syncthreads();
    if (kc + 1 < 16) {
      int nb = (kc + 1) & 1;
#pragma unroll
      for (int i = 0; i < 2; ++i) {
        int id = t + 256 * i;
        int c4 = id >> 7, r = id & 127;
        *(uint4*)(als[nb] + c4 * 2048 + r * 16) =
            *(const uint4*)((const char*)wp2T + (size_t)r * 1024 + ((kc + 1) * 4 + c4) * 16);
      }
      int c4 = t >> 6, r = t & 63;
      *(uint4*)(bls[nb] + c4 * 1024 + r * 16) =
          *(const uint4*)((const char*)h2n + (size_t)(n0 + r) * 1024 + ((kc + 1) * 4 + c4) * 16);
    }
    int buf = kc & 1;
    bf16x8 bf1 = *(const bf16x8*)(bls[buf] + quad * 1024 + (wbase + l15) * 16);
#pragma unroll
    for (int mt = 0; mt < 8; ++mt) {
      bf16x8 af = *(const bf16x8*)(als[buf] + quad * 2048 + (mt * 16 + l15) * 16);
      acc[mt] = __builtin_amdgcn_mfma_f32_16x16x32_bf16(af, bf1, acc[mt], 0, 0, 0);
    }
  }

#pragma unroll
  for (int mt = 0; mt < 8; ++mt) {
    float s = 0.f, ss = 0.f;
    int pos = posb + wbase + l15;
#pragma unroll
    for (int r = 0; r < 4; ++r) {
      float v = acc[mt][r];
      s += v;
      ss += v * v;
      int co = mt * 16 + quad * 4 + r;
      h3[(size_t)(b * 128 + co) * 1024 + pos] = v;
    }
#pragma unroll
    for (int off = 32; off; off >>= 1) {
      s += __shfl_down(s, off, 64);
      ss += __shfl_down(ss, off, 64);
    }
    if (lane == 0) { red[wave][mt][0] = s; red[wave][mt][1] = ss; }
  }
  __syncthreads();
  if (t < 16) {
    int mt = t >> 1, which = t & 1;
    float v = red[0][mt][which] + red[1][mt][which] + red[2][mt][which] + red[3][mt][which];
    atomicAdd(&stats3[(b * 8 + mt) * 2 + which], v);
  }
}

// ---------------- final GN+SiLU -> d_out (fp32) ----------------------------
__global__ void out_kernel(const float* __restrict__ h3, const float* __restrict__ stats,
                           const float* __restrict__ gs, const float* __restrict__ gb,
                           float* __restrict__ out) {
  const int total = B_ * COUT_ * 1024;
  for (int idx = blockIdx.x * blockDim.x + threadIdx.x; idx < total; idx += gridDim.x * blockDim.x) {
    int c = (idx >> 10) & 127;
    int b = idx >> 17;
    int bg = b * 8 + (c >> 4);
    float S = stats[bg * 2], SS = stats[bg * 2 + 1];
    float mean = S * (1.f / 16384.f);
    float var = SS * (1.f / 16384.f) - mean * mean;
    float rstd = rsqrtf(var + 1e-5f);
    float v = (h3[idx] - mean) * rstd * gs[c] + gb[c];
    out[idx] = siluf(v);
  }
}

extern "C" void kernel_launch(void* const* d_in, const int* in_sizes, int n_in,
                              void* d_out, int out_size, void* d_ws, size_t ws_size,
                              hipStream_t stream) {
  const float* x = (const float*)d_in[0];
  const float* w_exp = (const float*)d_in[1];
  const float* gn_exp_s = (const float*)d_in[2];
  const float* gn_exp_b = (const float*)d_in[3];
  const float* w1 = (const float*)d_in[4];
  const float* b1 = (const float*)d_in[5];
  const float* w2 = (const float*)d_in[6];
  const float* b2 = (const float*)d_in[7];
  const float* w_pw1 = (const float*)d_in[8];
  const float* gn1_s = (const float*)d_in[9];
  const float* gn1_b = (const float*)d_in[10];
  const float* w_dw = (const float*)d_in[11];
  const float* gn2_s = (const float*)d_in[12];
  const float* gn2_b = (const float*)d_in[13];
  const float* w_pw2 = (const float*)d_in[14];
  const float* gn3_s = (const float*)d_in[15];
  const float* gn3_b = (const float*)d_in[16];

  char* ws = (char*)d_ws;
  const size_t WP1T_OFF = 16384;
  const size_t WP2T_OFF = WP1T_OFF + 131072;
  const size_t XT_OFF = WP2T_OFF + 131072;                 // 278528
  const size_t WT_OFF = XT_OFF + 16777216;                 // 17055744
  const size_t YS_OFF = WT_OFF + 2359296;                  // 19415040
  const size_t NEEDED = YS_OFF + 134217728;                // 153632768
  if (ws_size < NEEDED) return;

  float* wts = (float*)ws;
  float* stats1 = (float*)(ws + 1024);
  float* stats2 = (float*)(ws + 2048);
  float* stats3 = (float*)(ws + 3072);
  float* statsE = (float*)(ws + 4096);
  bf16* wp1T = (bf16*)(ws + WP1T_OFF);
  bf16* wp2T = (bf16*)(ws + WP2T_OFF);
  bf16* xT = (bf16*)(ws + XT_OFF);
  bf16* ccl = (bf16*)(ws + XT_OFF);
  bf16* wT = (bf16*)(ws + WT_OFF);
  bf16* ys = (bf16*)(ws + YS_OFF);
  bf16* h1cl = (bf16*)(ws + YS_OFF);
  bf16* h2cl = (bf16*)(ws + YS_OFF + 67108864);
  float* h3 = (float*)(ws + YS_OFF + 83886080);

  hipMemsetAsync(ws, 0, 16384, stream);
  gate_kernel<<<1, 64, 0, stream>>>(w1, b1, w2, b2, wts);
  xt_kernel<<<B_ * 64, 256, 0, stream>>>(x, xT);
  wt_kernel<<<4608, 256, 0, stream>>>(w_exp, wT);
  wpT_kernel<<<512, 256, 0, stream>>>(w_pw1, w_pw2, wp1T, wp2T);
  conv_mfma<<<E_ * B_ * 16, 256, 0, stream>>>(xT, wT, statsE, ys);
  finalize_stats<<<4, 256, 0, stream>>>(statsE, 1024, 1.f / 65536.f);
  combine_cl<<<B_ * 64, 256, 0, stream>>>(x, ys, statsE, gn_exp_s, gn_exp_b, wts, ccl);
  pw1_mfma<<<4 * 512, 256, 0, stream>>>(ccl, wp1T, h1cl, stats1);
  finalize_stats<<<1, 128, 0, stream>>>(stats1, 128, 1.f / 262144.f);
  dw_cl<<<B_ * 64 * 8, 256, 0, stream>>>(h1cl, w_dw, stats1, gn1_s, gn1_b, h2cl, stats2);
  finalize_stats<<<1, 128, 0, stream>>>(stats2, 128, 1.f / 262144.f);
  norm2_kernel<<<4096, 256, 0, stream>>>(h2cl, stats2, gn2_s, gn2_b);
  pw2_mfma<<<256, 256, 0, stream>>>(h2cl, wp2T, h3, stats3);
  out_kernel<<<1024, 256, 0, stream>>>(h3, stats3, gn3_s, gn3_b, (float*)d_out);
}

// Round 5
// 496.394 us; speedup vs baseline: 6.8217x; 1.1922x over previous
//
#include <hip/hip_runtime.h>
#include <hip/hip_bf16.h>

// ---------------------------------------------------------------------------
// PCELayer R5 = R4 with dw_cl rewritten: GN1+SiLU applied ONCE per element
// into an LDS-staged tile (18 rows x 66 padded w-slots x 16 hc), then 3x3
// depthwise stencil via sliding register window. R4's dw recomputed
// normalize+SiLU 9x per output (2 transcendentals each) -> VALUBusy 84%.
// Everything else unchanged from R4.
// Workspace (153.6 MB):
//   head 16K: wts/stats1/stats2/stats3/statsE
//   wp1T 128K | wp2T 128K
//   XT 16.8M (-> combined_cl after conv)
//   WT 2.4M
//   YS 134.2M (-> h1cl 67M | h2cl 16.8M | h3 8.4M after combine)
// ---------------------------------------------------------------------------

#define B_ 16
#define CIN_ 128
#define COUT_ 128
#define H_ 64
#define W_ 64
#define HW_ 4096
#define E_ 8
#define FF_ 8
#define GC_ 32
#define HID_ 64
#define HC_ 512

typedef __hip_bfloat16 bf16;
typedef __bf16 bf16x8 __attribute__((ext_vector_type(8)));
typedef float f32x4 __attribute__((ext_vector_type(4)));

__device__ __forceinline__ float siluf(float v) { return v / (1.f + __expf(-v)); }
__device__ __forceinline__ float bf2f(bf16 v) { return __bfloat162float(v); }
__device__ __forceinline__ bf16 f2bf(float v) { return __float2bfloat16(v); }

// ---------------- router gate ----------------------------------------------
__global__ void gate_kernel(const float* __restrict__ w1, const float* __restrict__ b1,
                            const float* __restrict__ w2, const float* __restrict__ b2,
                            float* __restrict__ wts) {
  int p = threadIdx.x;
  if (p >= 16) return;
  int i = p >> 2, j = p & 3;
  float cy = (i + 0.5f) * 0.25f;
  float cx = (j + 0.5f) * 0.25f;
  float feats[GC_];
#pragma unroll
  for (int f = 0; f < FF_; ++f) {
    float fr = 3.14159265358979f * (float)(1 << f);
    float ay = cy * fr, ax = cx * fr;
    feats[f] = sinf(ay);
    feats[FF_ + f] = cosf(ay);
    feats[2 * FF_ + f] = sinf(ax);
    feats[3 * FF_ + f] = cosf(ax);
  }
  float hid[HID_];
  for (int k = 0; k < HID_; ++k) {
    float a = b1[k];
#pragma unroll
    for (int m = 0; m < GC_; ++m) a = fmaf(feats[m], w1[m * HID_ + k], a);
    hid[k] = siluf(a);
  }
  float lg[E_];
  float mx = -1e30f;
#pragma unroll
  for (int e = 0; e < E_; ++e) {
    float a = b2[e];
    for (int k = 0; k < HID_; ++k) a = fmaf(hid[k], w2[k * E_ + e], a);
    lg[e] = a;
    mx = fmaxf(mx, a);
  }
  float s = 0.f;
#pragma unroll
  for (int e = 0; e < E_; ++e) { lg[e] = __expf(lg[e] - mx); s += lg[e]; }
  float inv = 1.f / s;
#pragma unroll
  for (int e = 0; e < E_; ++e) wts[p * E_ + e] = lg[e] * inv;
}

// ---------------- x -> channels-last bf16 ----------------------------------
__global__ __launch_bounds__(256) void xt_kernel(const float* __restrict__ x,
                                                 bf16* __restrict__ xT) {
  __shared__ float t[128][65];
  int b = blockIdx.x >> 6, h = blockIdx.x & 63;
  int tid = threadIdx.x;
  int w = tid & 63, c4 = tid >> 6;
  const float* xb = x + ((size_t)(b * 128) * 64 + h) * 64;
#pragma unroll 4
  for (int rep = 0; rep < 32; ++rep) {
    int ci = rep * 4 + c4;
    t[ci][w] = xb[(size_t)ci * HW_ + w];
  }
  __syncthreads();
  bf16* dst = xT + (size_t)(b * 64 + h) * 8192;
#pragma unroll 4
  for (int rep = 0; rep < 32; ++rep) {
    int o = rep * 256 + tid;
    int cg = o >> 9, w2 = (o >> 3) & 63, lo = o & 7;
    dst[o] = f2bf(t[cg * 8 + lo][w2]);
  }
}

// ---------------- w_exp -> wT bf16 -----------------------------------------
__global__ void wt_kernel(const float* __restrict__ w_exp, bf16* __restrict__ wT) {
  int idx = blockIdx.x * 256 + threadIdx.x;
  if (idx >= 1179648) return;
  int lo = idx & 7;
  int co = (idx >> 3) & 127;
  int cg = (idx >> 10) & 15;
  int rest = idx >> 14;
  int tap = rest % 9, e = rest / 9;
  int ci = cg * 8 + lo;
  wT[idx] = f2bf(w_exp[(((size_t)(e * 128 + co) * 128 + ci) * 9) + tap]);
}

// ---------------- pw weights fp32 -> bf16 ----------------------------------
__global__ void wpT_kernel(const float* __restrict__ w_pw1, const float* __restrict__ w_pw2,
                           bf16* __restrict__ wp1T, bf16* __restrict__ wp2T) {
  int idx = blockIdx.x * 256 + threadIdx.x;
  if (idx < 65536) wp1T[idx] = f2bf(w_pw1[idx]);
  else if (idx < 131072) wp2T[idx - 65536] = f2bf(w_pw2[idx - 65536]);
}

// ---------------- expert conv via MFMA (v2) --------------------------------
__global__ __launch_bounds__(256, 2) void conv_mfma(
    const bf16* __restrict__ xT, const bf16* __restrict__ wT,
    float* __restrict__ statsE, bf16* __restrict__ ys) {
  __shared__ __align__(16) char xls[8 * 6144];   // [cg(8)][r(6)][w(64)]x16B = 48K
  __shared__ __align__(16) char wls[8 * 2048];   // [cg(8)][co(128)]x16B = 16K
  __shared__ float red[4][8][2];

  int blk = blockIdx.x;
  int rt = blk & 15, b = (blk >> 4) & 15, e = blk >> 8;
  int tid = threadIdx.x, lane = tid & 63, wave = tid >> 6;
  int quad = lane >> 4, l15 = lane & 15;
  int h0 = rt * 4;
  int h_local = wave;

  f32x4 acc[8][4];
#pragma unroll
  for (int mt = 0; mt < 8; ++mt)
#pragma unroll
    for (int nt = 0; nt < 4; ++nt) acc[mt][nt] = (f32x4){0.f, 0.f, 0.f, 0.f};

  bf16x8 bz;
#pragma unroll
  for (int j = 0; j < 8; ++j) bz[j] = (__bf16)0.f;

  for (int half = 0; half < 2; ++half) {
    __syncthreads();
#pragma unroll
    for (int s = 0; s < 12; ++s) {
      int seg = wave * 12 + s;
      int cg = seg / 6, r = seg % 6;
      int h = h0 - 1 + r;
      char* ldst = xls + cg * 6144 + r * 1024 + lane * 16;
      if ((unsigned)h < 64u) {
        const uint4* g = (const uint4*)((const char*)xT +
            ((size_t)((b * 64 + h) * 16) + half * 8 + cg) * 1024) + lane;
        *(uint4*)ldst = *g;
      } else {
        *(uint4*)ldst = make_uint4(0u, 0u, 0u, 0u);
      }
    }
    for (int tap = 0; tap < 9; ++tap) {
      int dr = tap / 3, ds = tap % 3;
      __syncthreads();
#pragma unroll
      for (int s = 0; s < 4; ++s) {
        int seg = wave * 4 + s;
        int cg = seg >> 1, cb = seg & 1;
        const uint4* g = (const uint4*)((const char*)wT +
            ((size_t)(((e * 9 + tap) * 16) + half * 8 + cg) * 128 + cb * 64) * 16) + lane;
        *(uint4*)(wls + cg * 2048 + cb * 1024 + lane * 16) = *g;
      }
      __syncthreads();
      int r_local = h_local + dr;
#pragma unroll
      for (int kc = 0; kc < 2; ++kc) {
        int cgq = kc * 4 + quad;
        bf16x8 af[8];
#pragma unroll
        for (int mt = 0; mt < 8; ++mt)
          af[mt] = *(const bf16x8*)(wls + cgq * 2048 + (mt * 16 + l15) * 16);
        bf16x8 bfr[4];
#pragma unroll
        for (int nt = 0; nt < 4; ++nt) {
          int w = nt * 16 + l15;
          int wsrc = w + ds - 1;
          bool valid = (unsigned)wsrc < 64u;
          int wc = valid ? wsrc : 0;
          bf16x8 v = *(const bf16x8*)(xls + cgq * 6144 + (r_local * 64 + wc) * 16);
          bfr[nt] = valid ? v : bz;
        }
#pragma unroll
        for (int mt = 0; mt < 8; ++mt)
#pragma unroll
          for (int nt = 0; nt < 4; ++nt)
            acc[mt][nt] = __builtin_amdgcn_mfma_f32_16x16x32_bf16(
                af[mt], bfr[nt], acc[mt][nt], 0, 0, 0);
      }
    }
  }

  int hh = h0 + h_local;
  bf16* yb = ys + (size_t)((e * 16 + b) * 128) * 4096;
#pragma unroll
  for (int mt = 0; mt < 8; ++mt) {
    float s = 0.f, ss = 0.f;
#pragma unroll
    for (int nt = 0; nt < 4; ++nt) {
      int w = nt * 16 + l15;
      int pos = hh * 64 + w;
#pragma unroll
      for (int r = 0; r < 4; ++r) {
        float v = acc[mt][nt][r];
        s += v;
        ss += v * v;
        int co = mt * 16 + quad * 4 + r;
        yb[(size_t)co * 4096 + pos] = f2bf(v);
      }
    }
#pragma unroll
    for (int off = 32; off; off >>= 1) {
      s += __shfl_down(s, off, 64);
      ss += __shfl_down(ss, off, 64);
    }
    if (lane == 0) { red[wave][mt][0] = s; red[wave][mt][1] = ss; }
  }
  __syncthreads();
  if (tid < 16) {
    int g = tid >> 1, which = tid & 1;
    float t = red[0][g][which] + red[1][g][which] + red[2][g][which] + red[3][g][which];
    atomicAdd(&statsE[((e * 16 + b) * 8 + g) * 2 + which], t);
  }
}

// ---------------- generic stats finalize: raw S/SS -> mean/rstd ------------
__global__ void finalize_stats(float* __restrict__ st, int n, float inv) {
  int i = blockIdx.x * 256 + threadIdx.x;
  if (i >= n) return;
  float S = st[i * 2], SS = st[i * 2 + 1];
  float mean = S * inv;
  float var = SS * inv - mean * mean;
  st[i * 2] = mean;
  st[i * 2 + 1] = rsqrtf(var + 1e-5f);
}

// ---------------- combine -> bf16 channels-last ----------------------------
__global__ __launch_bounds__(256) void combine_cl(
    const float* __restrict__ x, const bf16* __restrict__ ys,
    const float* __restrict__ st, const float* __restrict__ gns,
    const float* __restrict__ gnb, const float* __restrict__ wts,
    bf16* __restrict__ ccl) {
  __shared__ bf16 tile[64][132];
  int b = blockIdx.x >> 6, h = blockIdx.x & 63;
  int t = threadIdx.x;
  int w32 = t & 31, coq = t >> 5;
  float m_[8], r_[8];
#pragma unroll
  for (int e = 0; e < 8; ++e) {
    m_[e] = st[((e * 16 + b) * 8 + coq) * 2];
    r_[e] = st[((e * 16 + b) * 8 + coq) * 2 + 1];
  }
#pragma unroll
  for (int wt2 = 0; wt2 < 2; ++wt2) {
    int w = wt2 * 32 + w32;
    int pid = (h >> 4) * 4 + (w >> 4);
    int pos = h * 64 + w;
    float wt_[8];
#pragma unroll
    for (int e = 0; e < 8; ++e) wt_[e] = wts[pid * 8 + e];
    for (int coi = 0; coi < 16; ++coi) {
      int co = coq * 16 + coi;
      float v = x[((size_t)(b * 128 + co) << 12) + pos];
#pragma unroll
      for (int e = 0; e < 8; ++e) {
        float y = bf2f(ys[((size_t)((e * 16 + b) * 128 + co) << 12) + pos]);
        float yn = (y - m_[e]) * r_[e] * gns[e * 128 + co] + gnb[e * 128 + co];
        v += siluf(yn) * wt_[e];
      }
      tile[w][co] = f2bf(v);
    }
  }
  __syncthreads();
  int row = t >> 2, q = t & 3;
  char* dst = (char*)ccl + ((size_t)(b * 4096 + h * 64 + row)) * 256 + q * 64;
  const char* src = (const char*)&tile[row][0] + q * 64;
#pragma unroll
  for (int i = 0; i < 4; ++i)
    *(uint4*)(dst + i * 16) = *(const uint4*)(src + i * 16);
}

// ---------------- pw1 MFMA: h1[hc=512][n=65536] = w[hc][ci] @ ccl[n][ci] ---
__global__ __launch_bounds__(256) void pw1_mfma(
    const bf16* __restrict__ ccl, const bf16* __restrict__ wp1T,
    bf16* __restrict__ h1cl, float* __restrict__ stats1) {
  __shared__ __align__(16) char ls[65536];  // als 32K | bls 32K ; reused as tile
  __shared__ float red[4][2][2];
  char* als = ls;
  char* bls = ls + 32768;
  int blk = blockIdx.x;
  int ntile = blk & 511, mtile = blk >> 9;
  int n0 = ntile * 128, m0 = mtile * 128;
  int t = threadIdx.x, lane = t & 63, wave = t >> 6;
  int quad = lane >> 4, l15 = lane & 15;
  int b = n0 >> 12;

#pragma unroll
  for (int i = 0; i < 8; ++i) {
    int id = t + 256 * i;
    int r = id >> 4, c = id & 15;
    *(uint4*)(als + c * 2048 + r * 16) =
        *(const uint4*)((const char*)wp1T + (size_t)(m0 + r) * 256 + c * 16);
    *(uint4*)(bls + c * 2048 + r * 16) =
        *(const uint4*)((const char*)ccl + (size_t)(n0 + r) * 256 + c * 16);
  }
  __syncthreads();

  f32x4 acc[8][2];
#pragma unroll
  for (int mt = 0; mt < 8; ++mt)
#pragma unroll
    for (int nt = 0; nt < 2; ++nt) acc[mt][nt] = (f32x4){0.f, 0.f, 0.f, 0.f};

#pragma unroll
  for (int kc = 0; kc < 4; ++kc) {
    int cgq = kc * 4 + quad;
    bf16x8 af[8];
#pragma unroll
    for (int mt = 0; mt < 8; ++mt)
      af[mt] = *(const bf16x8*)(als + cgq * 2048 + (mt * 16 + l15) * 16);
    bf16x8 bfr[2];
#pragma unroll
    for (int nt = 0; nt < 2; ++nt)
      bfr[nt] = *(const bf16x8*)(bls + cgq * 2048 + (wave * 32 + nt * 16 + l15) * 16);
#pragma unroll
    for (int mt = 0; mt < 8; ++mt)
#pragma unroll
      for (int nt = 0; nt < 2; ++nt)
        acc[mt][nt] = __builtin_amdgcn_mfma_f32_16x16x32_bf16(
            af[mt], bfr[nt], acc[mt][nt], 0, 0, 0);
  }

  __syncthreads();  // everyone done with als/bls
  float s[2] = {0.f, 0.f}, ss[2] = {0.f, 0.f};
  bf16* tile = (bf16*)ls;  // row stride 132 elems = 264 B
#pragma unroll
  for (int mt = 0; mt < 8; ++mt) {
    int gi = mt >> 2;
#pragma unroll
    for (int nt = 0; nt < 2; ++nt) {
      int n = wave * 32 + nt * 16 + l15;
#pragma unroll
      for (int r = 0; r < 4; ++r) {
        float v = acc[mt][nt][r];
        s[gi] += v;
        ss[gi] += v * v;
        tile[n * 132 + mt * 16 + quad * 4 + r] = f2bf(v);
      }
    }
  }
#pragma unroll
  for (int gi = 0; gi < 2; ++gi) {
#pragma unroll
    for (int off = 32; off; off >>= 1) {
      s[gi] += __shfl_down(s[gi], off, 64);
      ss[gi] += __shfl_down(ss[gi], off, 64);
    }
  }
  if (lane == 0) {
    red[wave][0][0] = s[0]; red[wave][0][1] = ss[0];
    red[wave][1][0] = s[1]; red[wave][1][1] = ss[1];
  }
  __syncthreads();
  if (t < 4) {
    int gi = t >> 1, which = t & 1;
    float v = red[0][gi][which] + red[1][gi][which] + red[2][gi][which] + red[3][gi][which];
    atomicAdd(&stats1[(b * 8 + mtile * 2 + gi) * 2 + which], v);
  }
#pragma unroll
  for (int i = 0; i < 8; ++i) {
    int id = t + 256 * i;             // 0..2047
    int r = id >> 4, q = id & 15;     // 128 rows x 16 chunks of 16B
    char* dst = (char*)h1cl + (size_t)(n0 + r) * 1024 + m0 * 2 + q * 16;
    const char* src = (const char*)tile + r * 264 + q * 16;
    *(uint4*)dst = *(const uint4*)src;
  }
}

// ---------------- dw3x3 v2: LDS-staged GN1+SiLU tile + sliding stencil -----
// grid: b(16) x hcg(32 groups of 16 hc) x ht(4 tiles of 16 rows) = 2048.
// Stage 18 rows x 66 w-slots (zero-padded halo) x 16 hc normalized bf16 in
// LDS (38 KB). Compute: thread = (w, hc-quarter of 4), 16 rows slide.
__global__ __launch_bounds__(256) void dw_cl(
    const bf16* __restrict__ h1cl, const float* __restrict__ w_dw,
    const float* __restrict__ st1, const float* __restrict__ gs,
    const float* __restrict__ gb, bf16* __restrict__ h2cl,
    float* __restrict__ stats2) {
  __shared__ __align__(16) bf16 tile[18 * 66 * 16];  // 38016 B
  __shared__ float red2[4][2];
  int blk = blockIdx.x;
  int ht = blk & 3, hcg = (blk >> 2) & 31, b = blk >> 7;
  int h0 = ht * 16;
  int hc0 = hcg * 16;
  int hcb = hcg >> 2;  // 64-hc GN group
  int t = threadIdx.x;

  float mean = st1[(b * 8 + hcb) * 2], rstd = st1[(b * 8 + hcb) * 2 + 1];
  float scale[16], shift[16];
#pragma unroll
  for (int j = 0; j < 16; ++j) {
    float g = gs[hc0 + j];
    scale[j] = rstd * g;
    shift[j] = gb[hc0 + j] - mean * rstd * g;
  }

  // ---- stage: 18 x 66 (row, wslot) pairs; wslot 0 and 65 are zero pad ----
  for (int i = 0; i < 5; ++i) {
    int idx = t + 256 * i;
    if (idx >= 1188) break;
    int row = idx / 66, wslot = idx - row * 66;
    int hh = h0 - 1 + row;
    int w = wslot - 1;
    int swz = (wslot >> 2) & 3;  // quarter swizzle base
    bf16* dst = tile + (row * 66 + wslot) * 16;
    if ((unsigned)hh < 64u && (unsigned)w < 64u) {
      const char* p = (const char*)h1cl + ((size_t)(b * 4096 + hh * 64 + w) * 512 + hc0) * 2;
      uint4 a0 = *(const uint4*)p;
      uint4 a1 = *(const uint4*)(p + 16);
      const bf16* pv = (const bf16*)&a0;
      const bf16* pv1 = (const bf16*)&a1;
      bf16 outv[16];
#pragma unroll
      for (int j = 0; j < 8; ++j)
        outv[j] = f2bf(siluf(bf2f(pv[j]) * scale[j] + shift[j]));
#pragma unroll
      for (int j = 0; j < 8; ++j)
        outv[8 + j] = f2bf(siluf(bf2f(pv1[j]) * scale[8 + j] + shift[8 + j]));
      // place logical quarter qq at physical slot (qq+swz)&3
#pragma unroll
      for (int qq = 0; qq < 4; ++qq) {
        int ph = (qq + swz) & 3;
        *(uint2*)(dst + ph * 4) = *(const uint2*)(outv + qq * 4);
      }
    } else {
      *(uint4*)dst = make_uint4(0u, 0u, 0u, 0u);
      *(uint4*)(dst + 8) = make_uint4(0u, 0u, 0u, 0u);
    }
  }
  __syncthreads();

  // ---- compute: thread = (w, quarter q of 4 hc), slide over 16 rows ----
  int w = t & 63, q = t >> 6;
  float wv[9][4];
#pragma unroll
  for (int j = 0; j < 4; ++j) {
    int hc = hc0 + q * 4 + j;
#pragma unroll
    for (int tap = 0; tap < 9; ++tap) wv[tap][j] = w_dw[hc * 9 + tap];
  }

  f32x4 win[3][3];  // [ring(row%3)][dw]
  float acc_s = 0.f, acc_ss = 0.f;

  // helper macro-ish lambda: load 4 bf16 from staged tile with swizzle
  auto ld4 = [&](int r, int dwi) -> f32x4 {
    int slot = w + dwi;
    int ph = (q + (slot >> 2)) & 3;
    const bf16* p = tile + (r * 66 + slot) * 16 + ph * 4;
    uint2 u = *(const uint2*)p;
    const bf16* pb = (const bf16*)&u;
    return (f32x4){bf2f(pb[0]), bf2f(pb[1]), bf2f(pb[2]), bf2f(pb[3])};
  };

#pragma unroll
  for (int dwi = 0; dwi < 3; ++dwi) {
    win[0][dwi] = ld4(0, dwi);
    win[1][dwi] = ld4(1, dwi);
  }
#pragma unroll
  for (int orow = 0; orow < 16; ++orow) {
    int rnew = orow + 2;
    int ringn = rnew % 3;
#pragma unroll
    for (int dwi = 0; dwi < 3; ++dwi) win[ringn][dwi] = ld4(rnew, dwi);
    f32x4 acc = (f32x4){0.f, 0.f, 0.f, 0.f};
#pragma unroll
    for (int dr = 0; dr < 3; ++dr) {
      int ring = (orow + dr) % 3;
#pragma unroll
      for (int dwi = 0; dwi < 3; ++dwi) {
#pragma unroll
        for (int j = 0; j < 4; ++j)
          acc[j] = fmaf(win[ring][dwi][j], wv[dr * 3 + dwi][j], acc[j]);
      }
    }
#pragma unroll
    for (int j = 0; j < 4; ++j) { acc_s += acc[j]; acc_ss += acc[j] * acc[j]; }
    if (!(orow & 1) && !(w & 1)) {
      int hglob = h0 + orow;
      int pos2 = (hglob >> 1) * 32 + (w >> 1);
      bf16 tmp[4];
#pragma unroll
      for (int j = 0; j < 4; ++j) tmp[j] = f2bf(acc[j]);
      *(uint2*)((char*)h2cl + ((size_t)(b * 1024 + pos2) * 512 + hc0 + q * 4) * 2) =
          *(const uint2*)tmp;
    }
  }

  // ---- stats reduction: one atomic pair per block into (b, hcb) ----
#pragma unroll
  for (int off = 32; off; off >>= 1) {
    acc_s += __shfl_down(acc_s, off, 64);
    acc_ss += __shfl_down(acc_ss, off, 64);
  }
  int wave = t >> 6;
  if ((t & 63) == 0) { red2[wave][0] = acc_s; red2[wave][1] = acc_ss; }
  __syncthreads();
  if (t < 2) {
    float v = red2[0][t] + red2[1][t] + red2[2][t] + red2[3][t];
    atomicAdd(&stats2[(b * 8 + hcb) * 2 + t], v);
  }
}

// ---------------- norm2 in-place on compact h2cl ---------------------------
__global__ void norm2_kernel(bf16* __restrict__ h2, const float* __restrict__ st2,
                             const float* __restrict__ gs, const float* __restrict__ gb) {
  int tg = blockIdx.x * 256 + threadIdx.x;
  int e8 = tg * 8;
  int hc0 = e8 & 511;
  int rest = e8 >> 9;
  int bq = rest >> 10;
  int g = hc0 >> 6;
  float mean = st2[(bq * 8 + g) * 2], rstd = st2[(bq * 8 + g) * 2 + 1];
  uint4 v = *(const uint4*)((const char*)h2 + (size_t)tg * 16);
  bf16* pv = (bf16*)&v;
  bf16 outv[8];
#pragma unroll
  for (int j = 0; j < 8; ++j) {
    float x = bf2f(pv[j]);
    x = (x - mean) * rstd * gs[hc0 + j] + gb[hc0 + j];
    outv[j] = f2bf(siluf(x));
  }
  *(uint4*)((char*)h2 + (size_t)tg * 16) = *(const uint4*)outv;
}

// ---------------- pw2 MFMA: h3[co=128][n=16384] = w[co][hc] @ h2n[n][hc] ---
__global__ __launch_bounds__(256) void pw2_mfma(
    const bf16* __restrict__ h2n, const bf16* __restrict__ wp2T,
    float* __restrict__ h3, float* __restrict__ stats3) {
  __shared__ __align__(16) char als[2][8192];
  __shared__ __align__(16) char bls[2][4096];
  __shared__ float red[4][8][2];
  int blk = blockIdx.x;
  int n0 = blk * 64;
  int b = n0 >> 10, posb = n0 & 1023;
  int t = threadIdx.x, lane = t & 63, wave = t >> 6;
  int quad = lane >> 4, l15 = lane & 15;
  int wbase = wave * 16;

  f32x4 acc[8];
#pragma unroll
  for (int mt = 0; mt < 8; ++mt) acc[mt] = (f32x4){0.f, 0.f, 0.f, 0.f};

  {
#pragma unroll
    for (int i = 0; i < 2; ++i) {
      int id = t + 256 * i;
      int c4 = id >> 7, r = id & 127;
      *(uint4*)(als[0] + c4 * 2048 + r * 16) =
          *(const uint4*)((const char*)wp2T + (size_t)r * 1024 + c4 * 16);
    }
    int c4 = t >> 6, r = t & 63;
    *(uint4*)(bls[0] + c4 * 1024 + r * 16) =
        *(const uint4*)((const char*)h2n + (size_t)(n0 + r) * 1024 + c4 * 16);
  }
  for (int kc = 0; kc < 16; ++kc) {
    __syncthreads();
    if (kc + 1 < 16) {
      int nb = (kc + 1) & 1;
#pragma unroll
      for (int i = 0; i < 2; ++i) {
        int id = t + 256 * i;
        int c4 = id >> 7, r = id & 127;
        *(uint4*)(als[nb] + c4 * 2048 + r * 16) =
            *(const uint4*)((const char*)wp2T + (size_t)r * 1024 + ((kc + 1) * 4 + c4) * 16);
      }
      int c4 = t >> 6, r = t & 63;
      *(uint4*)(bls[nb] + c4 * 1024 + r * 16) =
          *(const uint4*)((const char*)h2n + (size_t)(n0 + r) * 1024 + ((kc + 1) * 4 + c4) * 16);
    }
    int buf = kc & 1;
    bf16x8 bf1 = *(const bf16x8*)(bls[buf] + quad * 1024 + (wbase + l15) * 16);
#pragma unroll
    for (int mt = 0; mt < 8; ++mt) {
      bf16x8 af = *(const bf16x8*)(als[buf] + quad * 2048 + (mt * 16 + l15) * 16);
      acc[mt] = __builtin_amdgcn_mfma_f32_16x16x32_bf16(af, bf1, acc[mt], 0, 0, 0);
    }
  }

#pragma unroll
  for (int mt = 0; mt < 8; ++mt) {
    float s = 0.f, ss = 0.f;
    int pos = posb + wbase + l15;
#pragma unroll
    for (int r = 0; r < 4; ++r) {
      float v = acc[mt][r];
      s += v;
      ss += v * v;
      int co = mt * 16 + quad * 4 + r;
      h3[(size_t)(b * 128 + co) * 1024 + pos] = v;
    }
#pragma unroll
    for (int off = 32; off; off >>= 1) {
      s += __shfl_down(s, off, 64);
      ss += __shfl_down(ss, off, 64);
    }
    if (lane == 0) { red[wave][mt][0] = s; red[wave][mt][1] = ss; }
  }
  __syncthreads();
  if (t < 16) {
    int mt = t >> 1, which = t & 1;
    float v = red[0][mt][which] + red[1][mt][which] + red[2][mt][which] + red[3][mt][which];
    atomicAdd(&stats3[(b * 8 + mt) * 2 + which], v);
  }
}

// ---------------- final GN+SiLU -> d_out (fp32) ----------------------------
__global__ void out_kernel(const float* __restrict__ h3, const float* __restrict__ stats,
                           const float* __restrict__ gs, const float* __restrict__ gb,
                           float* __restrict__ out) {
  const int total = B_ * COUT_ * 1024;
  for (int idx = blockIdx.x * blockDim.x + threadIdx.x; idx < total; idx += gridDim.x * blockDim.x) {
    int c = (idx >> 10) & 127;
    int b = idx >> 17;
    int bg = b * 8 + (c >> 4);
    float S = stats[bg * 2], SS = stats[bg * 2 + 1];
    float mean = S * (1.f / 16384.f);
    float var = SS * (1.f / 16384.f) - mean * mean;
    float rstd = rsqrtf(var + 1e-5f);
    float v = (h3[idx] - mean) * rstd * gs[c] + gb[c];
    out[idx] = siluf(v);
  }
}

extern "C" void kernel_launch(void* const* d_in, const int* in_sizes, int n_in,
                              void* d_out, int out_size, void* d_ws, size_t ws_size,
                              hipStream_t stream) {
  const float* x = (const float*)d_in[0];
  const float* w_exp = (const float*)d_in[1];
  const float* gn_exp_s = (const float*)d_in[2];
  const float* gn_exp_b = (const float*)d_in[3];
  const float* w1 = (const float*)d_in[4];
  const float* b1 = (const float*)d_in[5];
  const float* w2 = (const float*)d_in[6];
  const float* b2 = (const float*)d_in[7];
  const float* w_pw1 = (const float*)d_in[8];
  const float* gn1_s = (const float*)d_in[9];
  const float* gn1_b = (const float*)d_in[10];
  const float* w_dw = (const float*)d_in[11];
  const float* gn2_s = (const float*)d_in[12];
  const float* gn2_b = (const float*)d_in[13];
  const float* w_pw2 = (const float*)d_in[14];
  const float* gn3_s = (const float*)d_in[15];
  const float* gn3_b = (const float*)d_in[16];

  char* ws = (char*)d_ws;
  const size_t WP1T_OFF = 16384;
  const size_t WP2T_OFF = WP1T_OFF + 131072;
  const size_t XT_OFF = WP2T_OFF + 131072;                 // 278528
  const size_t WT_OFF = XT_OFF + 16777216;                 // 17055744
  const size_t YS_OFF = WT_OFF + 2359296;                  // 19415040
  const size_t NEEDED = YS_OFF + 134217728;                // 153632768
  if (ws_size < NEEDED) return;

  float* wts = (float*)ws;
  float* stats1 = (float*)(ws + 1024);
  float* stats2 = (float*)(ws + 2048);
  float* stats3 = (float*)(ws + 3072);
  float* statsE = (float*)(ws + 4096);
  bf16* wp1T = (bf16*)(ws + WP1T_OFF);
  bf16* wp2T = (bf16*)(ws + WP2T_OFF);
  bf16* xT = (bf16*)(ws + XT_OFF);
  bf16* ccl = (bf16*)(ws + XT_OFF);
  bf16* wT = (bf16*)(ws + WT_OFF);
  bf16* ys = (bf16*)(ws + YS_OFF);
  bf16* h1cl = (bf16*)(ws + YS_OFF);
  bf16* h2cl = (bf16*)(ws + YS_OFF + 67108864);
  float* h3 = (float*)(ws + YS_OFF + 83886080);

  hipMemsetAsync(ws, 0, 16384, stream);
  gate_kernel<<<1, 64, 0, stream>>>(w1, b1, w2, b2, wts);
  xt_kernel<<<B_ * 64, 256, 0, stream>>>(x, xT);
  wt_kernel<<<4608, 256, 0, stream>>>(w_exp, wT);
  wpT_kernel<<<512, 256, 0, stream>>>(w_pw1, w_pw2, wp1T, wp2T);
  conv_mfma<<<E_ * B_ * 16, 256, 0, stream>>>(xT, wT, statsE, ys);
  finalize_stats<<<4, 256, 0, stream>>>(statsE, 1024, 1.f / 65536.f);
  combine_cl<<<B_ * 64, 256, 0, stream>>>(x, ys, statsE, gn_exp_s, gn_exp_b, wts, ccl);
  pw1_mfma<<<4 * 512, 256, 0, stream>>>(ccl, wp1T, h1cl, stats1);
  finalize_stats<<<1, 128, 0, stream>>>(stats1, 128, 1.f / 262144.f);
  dw_cl<<<B_ * 32 * 4, 256, 0, stream>>>(h1cl, w_dw, stats1, gn1_s, gn1_b, h2cl, stats2);
  finalize_stats<<<1, 128, 0, stream>>>(stats2, 128, 1.f / 262144.f);
  norm2_kernel<<<4096, 256, 0, stream>>>(h2cl, stats2, gn2_s, gn2_b);
  pw2_mfma<<<256, 256, 0, stream>>>(h2cl, wp2T, h3, stats3);
  out_kernel<<<1024, 256, 0, stream>>>(h3, stats3, gn3_s, gn3_b, (float*)d_out);
}